// Round 1
// baseline (4182.182 us; speedup 1.0000x reference)
//
#include <hip/hip_runtime.h>
#include <math.h>

// Problem constants
#define BB 16
#define NN 4096
#define NPTS (BB*NN)

// ---------------------------------------------------------------------------
// Layer 1 stats: y1 = w1@p + b1 (64 ch), accumulate per-channel sum/sumsq
// grid 256 x 256thr, 1 point/thread
__global__ void k_stats1(const float* __restrict__ pts, const float* __restrict__ w1,
                         const float* __restrict__ b1, float* __restrict__ part1) {
    __shared__ float sw[256];
    __shared__ float wred[2][4][64];
    int t = threadIdx.x;
    if (t < 192) sw[t] = w1[t];
    if (t < 64) sw[192 + t] = b1[t];
    __syncthreads();
    int g = blockIdx.x * 256 + t;
    float p0 = pts[g*3], p1 = pts[g*3+1], p2 = pts[g*3+2];
    int lane = t & 63, wv = t >> 6;
    for (int c = 0; c < 64; c++) {
        float y = fmaf(sw[c*3+2], p2, fmaf(sw[c*3+1], p1, fmaf(sw[c*3], p0, sw[192+c])));
        float s = y, q = y * y;
        #pragma unroll
        for (int o = 32; o > 0; o >>= 1) { s += __shfl_down(s, o); q += __shfl_down(q, o); }
        if (lane == 0) { wred[0][wv][c] = s; wred[1][wv][c] = q; }
    }
    __syncthreads();
    if (t < 64) {
        float s = wred[0][0][t] + wred[0][1][t] + wred[0][2][t] + wred[0][3][t];
        float q = wred[1][0][t] + wred[1][1][t] + wred[1][2][t] + wred[1][3][t];
        part1[blockIdx.x * 128 + t] = s;
        part1[blockIdx.x * 128 + 64 + t] = q;
    }
}

// Generic BN-stat finalize: grid = Cout blocks, 256 thr; computes s,t per channel
__global__ void k_fin(const float* __restrict__ part, int count, int stride, int sqoff,
                      const float* __restrict__ g, const float* __restrict__ be,
                      float* __restrict__ sout, float* __restrict__ tout) {
    int c = blockIdx.x, t = threadIdx.x;
    float s = 0.f, q = 0.f;
    for (int w = t; w < count; w += 256) { s += part[w*stride + c]; q += part[w*stride + sqoff + c]; }
    __shared__ float rs[4], rq[4];
    int lane = t & 63, wv = t >> 6;
    #pragma unroll
    for (int o = 32; o > 0; o >>= 1) { s += __shfl_down(s, o); q += __shfl_down(q, o); }
    if (lane == 0) { rs[wv] = s; rq[wv] = q; }
    __syncthreads();
    if (t == 0) {
        s = rs[0] + rs[1] + rs[2] + rs[3];
        q = rq[0] + rq[1] + rq[2] + rq[3];
        float mean = s / 65536.f;
        float var = q / 65536.f - mean * mean;
        float sc = g[c] * rsqrtf(var + 1e-5f);
        sout[c] = sc;
        tout[c] = be[c] - mean * sc;
    }
}

// l_feat = relu(s1*y1 + t1), layout [b][c][n]
__global__ void k_lfeat(const float* __restrict__ pts, const float* __restrict__ w1,
                        const float* __restrict__ b1, const float* __restrict__ s1,
                        const float* __restrict__ t1, float* __restrict__ lf) {
    __shared__ float sw[256], ss[64], st[64];
    int t = threadIdx.x;
    if (t < 192) sw[t] = w1[t];
    if (t < 64) { sw[192+t] = b1[t]; ss[t] = s1[t]; st[t] = t1[t]; }
    __syncthreads();
    int g = blockIdx.x * 256 + t;
    int b = g >> 12, n = g & 4095;
    float p0 = pts[g*3], p1 = pts[g*3+1], p2 = pts[g*3+2];
    for (int c = 0; c < 64; c++) {
        float y = fmaf(sw[c*3+2], p2, fmaf(sw[c*3+1], p1, fmaf(sw[c*3], p0, sw[192+c])));
        lf[((b<<6)+c)*4096 + n] = fmaxf(fmaf(ss[c], y, st[c]), 0.f);
    }
}

// conv3: y3 = w3@l_feat + b3 (512 ch). Stats (sum/sumsq/max per ch) + store ch 0..7 raw.
// grid 256 x 256thr, 1 point/thread; lf row in registers; w3 row uniform (scalar loads)
__global__ void k_conv3(const float* __restrict__ lf, const float* __restrict__ w3,
                        const float* __restrict__ b3, float* __restrict__ part3,
                        float* __restrict__ y38) {
    int t = threadIdx.x, blk = blockIdx.x;
    int g = blk * 256 + t, b = g >> 12, n = g & 4095;
    float lr[64];
    #pragma unroll
    for (int d = 0; d < 64; d++) lr[d] = lf[((b<<6)+d)*4096 + n];
    int lane = t & 63, wv = t >> 6, wg = blk * 4 + wv;
    for (int c = 0; c < 512; c++) {
        float acc = b3[c];
        #pragma unroll
        for (int d = 0; d < 64; d++) acc = fmaf(w3[(c<<6)+d], lr[d], acc);
        float s = acc, q = acc * acc, mx = acc;
        #pragma unroll
        for (int o = 32; o > 0; o >>= 1) {
            s += __shfl_down(s, o); q += __shfl_down(q, o);
            mx = fmaxf(mx, __shfl_down(mx, o));
        }
        if (lane == 0) {
            part3[wg*1536 + c] = s;
            part3[wg*1536 + 512 + c] = q;
            part3[wg*1536 + 1024 + c] = mx;
        }
        if (c < 8) y38[((b<<3)+c)*4096 + n] = acc;
    }
}

// gmax[b,c] = relu(s3*max_n(y3) + t3)   (s3>0 since g3~1)
__global__ void k_fin3b(const float* __restrict__ part3, const float* __restrict__ s3,
                        const float* __restrict__ t3, float* __restrict__ gmaxb) {
    int b = blockIdx.x, c = threadIdx.x;  // 16 x 512
    float mx = -__builtin_inff();
    for (int w = 0; w < 64; w++) mx = fmaxf(mx, part3[((b<<6)+w)*1536 + 1024 + c]);
    gmaxb[(b<<9)+c] = fmaxf(fmaf(s3[c], mx, t3[c]), 0.f);
}

// A1[o] = sum_{c<512} hw1[o,c];  G1[b,o] = sum_c hw1[o,576+c]*gmax[b,c]
__global__ void k_a1g1(const float* __restrict__ hw1, const float* __restrict__ gmaxb,
                       float* __restrict__ A1, float* __restrict__ G1) {
    int blk = blockIdx.x, t = threadIdx.x;
    if (blk == 16) {
        for (int o = t; o < 512; o += 256) {
            float s = 0.f;
            for (int c = 0; c < 512; c++) s += hw1[o*1088 + c];
            A1[o] = s;
        }
    } else {
        int b = blk;
        for (int o = t; o < 512; o += 256) {
            float s = 0.f;
            for (int c = 0; c < 512; c++) s = fmaf(hw1[o*1088 + 576 + c], gmaxb[(b<<9)+c], s);
            G1[(b<<9)+o] = s;
        }
    }
}

// KNN (exact numpy-order fp32, no FMA) + m[b,n] = max_k relu(s3[k]*y3[k,idx_k]+t3[k])
// grid 256 x 256thr (1 query/thread); candidate points staged in LDS in 2 phases
__global__ void k_knn(const float* __restrict__ pts, const float* __restrict__ y38,
                      const float* __restrict__ s3, const float* __restrict__ t3,
                      float* __restrict__ mbuf) {
    __shared__ float sp[2048 * 4];
    int t = threadIdx.x, blk = blockIdx.x;
    int b = blk >> 4, n = (blk & 15) * 256 + t;
    const float* pb = pts + (size_t)b * 4096 * 3;
    float q0 = pb[n*3], q1 = pb[n*3+1], q2 = pb[n*3+2];
    float qx2 = __fadd_rn(__fadd_rn(__fmul_rn(q0,q0), __fmul_rn(q1,q1)), __fmul_rn(q2,q2));
    float kd[8]; int ki[8];
    #pragma unroll
    for (int k = 0; k < 8; k++) { kd[k] = __builtin_inff(); ki[k] = 0x7fffffff; }
    for (int ph = 0; ph < 2; ph++) {
        __syncthreads();
        for (int i = t; i < 2048; i += 256) {
            int mm = (ph << 11) + i;
            float c0 = pb[mm*3], c1 = pb[mm*3+1], c2 = pb[mm*3+2];
            sp[i*4] = c0; sp[i*4+1] = c1; sp[i*4+2] = c2;
            sp[i*4+3] = __fadd_rn(__fadd_rn(__fmul_rn(c0,c0), __fmul_rn(c1,c1)), __fmul_rn(c2,c2));
        }
        __syncthreads();
        int mbase = ph << 11;
        for (int i = 0; i < 2048; i++) {
            float4 cp = *(const float4*)&sp[i*4];
            float dot = __fadd_rn(__fadd_rn(__fmul_rn(q0,cp.x), __fmul_rn(q1,cp.y)), __fmul_rn(q2,cp.z));
            float dist = __fsub_rn(__fadd_rn(qx2, cp.w), __fmul_rn(2.f, dot));
            int mm = mbase + i;
            if (dist < kd[7] || (dist == kd[7] && mm < ki[7])) {
                kd[7] = dist; ki[7] = mm;
                #pragma unroll
                for (int j = 7; j > 0; j--) {
                    bool sw = (kd[j] < kd[j-1]) || (kd[j] == kd[j-1] && ki[j] < ki[j-1]);
                    float td = sw ? kd[j-1] : kd[j]; float bd = sw ? kd[j] : kd[j-1];
                    int   ti = sw ? ki[j-1] : ki[j]; int   bi = sw ? ki[j] : ki[j-1];
                    kd[j] = td; ki[j] = ti; kd[j-1] = bd; ki[j-1] = bi;
                }
            }
        }
    }
    float mv = -__builtin_inff();
    #pragma unroll
    for (int k = 0; k < 8; k++) {
        float y = y38[((b<<3)+k)*4096 + ki[k]];
        mv = fmaxf(mv, fmaxf(fmaf(s3[k], y, t3[k]), 0.f));
    }
    mbuf[(b<<12)+n] = mv;
}

// h1 stats: pre1[o] = A1[o]*m + hw1[o,512:576]@lf + G1[b,o] + hb1[o]; sum/sumsq per ch
__global__ void k_h1s(const float* __restrict__ lf, const float* __restrict__ mbuf,
                      const float* __restrict__ G1, const float* __restrict__ A1,
                      const float* __restrict__ hw1, const float* __restrict__ hb1,
                      float* __restrict__ parth1) {
    int t = threadIdx.x, blk = blockIdx.x;
    int g = blk * 256 + t, b = g >> 12, n = g & 4095;
    float lr[64];
    #pragma unroll
    for (int d = 0; d < 64; d++) lr[d] = lf[((b<<6)+d)*4096 + n];
    float mval = mbuf[g];
    int lane = t & 63, wv = t >> 6, wg = blk * 4 + wv;
    for (int o = 0; o < 512; o++) {
        float acc = fmaf(A1[o], mval, hb1[o] + G1[(b<<9)+o]);
        #pragma unroll
        for (int d = 0; d < 64; d++) acc = fmaf(hw1[o*1088 + 512 + d], lr[d], acc);
        float s = acc, q = acc * acc;
        #pragma unroll
        for (int off = 32; off > 0; off >>= 1) { s += __shfl_down(s, off); q += __shfl_down(q, off); }
        if (lane == 0) { parth1[wg*1024 + o] = s; parth1[wg*1024 + 512 + o] = q; }
    }
}

// h2: recompute pre1 -> a1 (LDS) -> pre2 = hw2@a1 + hb2; store pre2 [b][n][c] + stats
// grid 4096 (16 pts/block) x 256thr
__global__ void k_h2(const float* __restrict__ lf, const float* __restrict__ mbuf,
                     const float* __restrict__ G1, const float* __restrict__ A1,
                     const float* __restrict__ hw1, const float* __restrict__ hb1,
                     const float* __restrict__ sh1, const float* __restrict__ th1,
                     const float* __restrict__ hw2, const float* __restrict__ hb2,
                     float* __restrict__ pre2, float* __restrict__ parth2) {
    __shared__ float lft[16 * 68];
    __shared__ float a1t[16 * 516];
    __shared__ float sm[16];
    int t = threadIdx.x, blk = blockIdx.x;
    int b = blk >> 8, n0 = (blk & 255) * 16;
    for (int i = t; i < 16 * 64; i += 256) {
        int p = i & 15, d = i >> 4;
        lft[p*68 + d] = lf[((b<<6)+d)*4096 + n0 + p];
    }
    if (t < 16) sm[t] = mbuf[(b<<12) + n0 + t];
    __syncthreads();
    for (int oi = 0; oi < 2; oi++) {
        int o = t + oi * 256;
        float base = hb1[o] + G1[(b<<9)+o];
        float a1c = A1[o];
        float wr[64];
        #pragma unroll
        for (int d4 = 0; d4 < 16; d4++) {
            float4 w = *(const float4*)&hw1[o*1088 + 512 + d4*4];
            wr[d4*4] = w.x; wr[d4*4+1] = w.y; wr[d4*4+2] = w.z; wr[d4*4+3] = w.w;
        }
        float s = sh1[o], tt = th1[o];
        for (int p = 0; p < 16; p++) {
            float acc = fmaf(a1c, sm[p], base);
            #pragma unroll
            for (int d4 = 0; d4 < 16; d4++) {
                float4 v = *(const float4*)&lft[p*68 + d4*4];
                acc = fmaf(wr[d4*4],   v.x, acc);
                acc = fmaf(wr[d4*4+1], v.y, acc);
                acc = fmaf(wr[d4*4+2], v.z, acc);
                acc = fmaf(wr[d4*4+3], v.w, acc);
            }
            a1t[p*516 + o] = fmaxf(fmaf(s, acc, tt), 0.f);
        }
    }
    __syncthreads();
    int c = t;
    float acc[16];
    float hb = hb2[c];
    #pragma unroll
    for (int p = 0; p < 16; p++) acc[p] = hb;
    for (int d4 = 0; d4 < 128; d4++) {
        float4 w = *(const float4*)&hw2[(c<<9) + d4*4];
        #pragma unroll
        for (int p = 0; p < 16; p++) {
            float4 v = *(const float4*)&a1t[p*516 + d4*4];
            acc[p] = fmaf(w.x, v.x, acc[p]);
            acc[p] = fmaf(w.y, v.y, acc[p]);
            acc[p] = fmaf(w.z, v.z, acc[p]);
            acc[p] = fmaf(w.w, v.w, acc[p]);
        }
    }
    float ssum = 0.f, ssq = 0.f;
    #pragma unroll
    for (int p = 0; p < 16; p++) {
        float v = acc[p];
        ssum += v; ssq = fmaf(v, v, ssq);
        pre2[(size_t)(((b<<12) + n0 + p) << 8) + c] = v;
    }
    parth2[blk*512 + c] = ssum;
    parth2[blk*512 + 256 + c] = ssq;
}

// h3 stats pass: a2 = relu(sh2*pre2+th2); pre3 = hw3@a2 + hb3; sum/sumsq per ch
// grid 2048 (32 pts/block) x 256thr
__global__ void k_h3s(const float* __restrict__ pre2, const float* __restrict__ sh2,
                      const float* __restrict__ th2, const float* __restrict__ hw3,
                      const float* __restrict__ hb3, float* __restrict__ parth3) {
    __shared__ float a2t[32 * 260];
    __shared__ float ss[256], st2[256];
    int t = threadIdx.x, blk = blockIdx.x;
    int b = blk >> 7, n0 = (blk & 127) * 32;
    ss[t] = sh2[t]; st2[t] = th2[t];
    __syncthreads();
    for (int i = t; i < 32 * 256; i += 256) {
        int c = i & 255, p = i >> 8;
        float v = pre2[(size_t)(((b<<12) + n0 + p) << 8) + c];
        a2t[p*260 + c] = fmaxf(fmaf(ss[c], v, st2[c]), 0.f);
    }
    __syncthreads();
    int c = t & 127, ph = t >> 7;
    float acc[16];
    float hb = hb3[c];
    #pragma unroll
    for (int p = 0; p < 16; p++) acc[p] = hb;
    for (int d4 = 0; d4 < 64; d4++) {
        float4 w = *(const float4*)&hw3[(c<<8) + d4*4];
        #pragma unroll
        for (int p = 0; p < 16; p++) {
            float4 v = *(const float4*)&a2t[(ph*16 + p)*260 + d4*4];
            acc[p] = fmaf(w.x, v.x, acc[p]);
            acc[p] = fmaf(w.y, v.y, acc[p]);
            acc[p] = fmaf(w.z, v.z, acc[p]);
            acc[p] = fmaf(w.w, v.w, acc[p]);
        }
    }
    float s = 0.f, q = 0.f;
    #pragma unroll
    for (int p = 0; p < 16; p++) { s += acc[p]; q = fmaf(acc[p], acc[p], q); }
    parth3[(blk*2 + ph)*256 + c] = s;
    parth3[(blk*2 + ph)*256 + 128 + c] = q;
}

// h4: recompute pre3 -> a3 (LDS) -> out = hw4@a3 + hb4, write (B,N,6)
__global__ void k_h4(const float* __restrict__ pre2, const float* __restrict__ sh2,
                     const float* __restrict__ th2, const float* __restrict__ hw3,
                     const float* __restrict__ hb3, const float* __restrict__ sh3,
                     const float* __restrict__ th3, const float* __restrict__ hw4,
                     const float* __restrict__ hb4, float* __restrict__ out) {
    __shared__ float a2t[32 * 260];
    __shared__ float a3t[32 * 132];
    __shared__ float ss[256], st2[256];
    int t = threadIdx.x, blk = blockIdx.x;
    int b = blk >> 7, n0 = (blk & 127) * 32;
    ss[t] = sh2[t]; st2[t] = th2[t];
    __syncthreads();
    for (int i = t; i < 32 * 256; i += 256) {
        int c = i & 255, p = i >> 8;
        float v = pre2[(size_t)(((b<<12) + n0 + p) << 8) + c];
        a2t[p*260 + c] = fmaxf(fmaf(ss[c], v, st2[c]), 0.f);
    }
    __syncthreads();
    int c = t & 127, ph = t >> 7;
    float acc[16];
    float hb = hb3[c];
    #pragma unroll
    for (int p = 0; p < 16; p++) acc[p] = hb;
    for (int d4 = 0; d4 < 64; d4++) {
        float4 w = *(const float4*)&hw3[(c<<8) + d4*4];
        #pragma unroll
        for (int p = 0; p < 16; p++) {
            float4 v = *(const float4*)&a2t[(ph*16 + p)*260 + d4*4];
            acc[p] = fmaf(w.x, v.x, acc[p]);
            acc[p] = fmaf(w.y, v.y, acc[p]);
            acc[p] = fmaf(w.z, v.z, acc[p]);
            acc[p] = fmaf(w.w, v.w, acc[p]);
        }
    }
    float s3v = sh3[c], t3v = th3[c];
    #pragma unroll
    for (int p = 0; p < 16; p++)
        a3t[(ph*16 + p)*132 + c] = fmaxf(fmaf(s3v, acc[p], t3v), 0.f);
    __syncthreads();
    int p = t >> 3, cc = t & 7;
    if (cc < 6) {
        float a = hb4[cc];
        for (int d4 = 0; d4 < 32; d4++) {
            float4 w = *(const float4*)&hw4[(cc<<7) + d4*4];
            float4 v = *(const float4*)&a3t[p*132 + d4*4];
            a = fmaf(w.x, v.x, a); a = fmaf(w.y, v.y, a);
            a = fmaf(w.z, v.z, a); a = fmaf(w.w, v.w, a);
        }
        out[(size_t)((b<<12) + n0 + p)*6 + cc] = a;
    }
}

extern "C" void kernel_launch(void* const* d_in, const int* in_sizes, int n_in,
                              void* d_out, int out_size, void* d_ws, size_t ws_size,
                              hipStream_t stream) {
    const float* pts  = (const float*)d_in[0];
    const float* w1   = (const float*)d_in[1];
    const float* b1   = (const float*)d_in[2];
    const float* g1   = (const float*)d_in[3];
    const float* be1  = (const float*)d_in[4];
    const float* w3   = (const float*)d_in[5];
    const float* b3   = (const float*)d_in[6];
    const float* g3   = (const float*)d_in[7];
    const float* be3  = (const float*)d_in[8];
    const float* hw1  = (const float*)d_in[9];
    const float* hb1  = (const float*)d_in[10];
    const float* hg1  = (const float*)d_in[11];
    const float* hbe1 = (const float*)d_in[12];
    const float* hw2  = (const float*)d_in[13];
    const float* hb2  = (const float*)d_in[14];
    const float* hg2  = (const float*)d_in[15];
    const float* hbe2 = (const float*)d_in[16];
    const float* hw3  = (const float*)d_in[17];
    const float* hb3  = (const float*)d_in[18];
    const float* hg3  = (const float*)d_in[19];
    const float* hbe3 = (const float*)d_in[20];
    const float* hw4  = (const float*)d_in[21];
    const float* hb4  = (const float*)d_in[22];
    (void)in_sizes; (void)n_in; (void)out_size; (void)ws_size;

    float* W = (float*)d_ws;
    size_t off = 0;
    auto alloc = [&](size_t n) { float* p = W + off; off += n; return p; };
    float* lf     = alloc(4194304);   // l_feat (B,64,N)
    float* y38    = alloc(524288);    // y3 raw, ch 0..7 (B,8,N)
    float* mbuf   = alloc(65536);     // m[b,n]
    float* gmaxb  = alloc(8192);      // gmax[b,c]
    float* G1     = alloc(8192);
    float* A1     = alloc(512);
    float* s1 = alloc(64);  float* t1 = alloc(64);
    float* s3 = alloc(512); float* t3 = alloc(512);
    float* sh1 = alloc(512); float* th1 = alloc(512);
    float* sh2 = alloc(256); float* th2 = alloc(256);
    float* sh3 = alloc(128); float* th3 = alloc(128);
    float* part1  = alloc(256 * 128);
    float* part3  = alloc(1024 * 1536);
    float* parth1 = alloc(1024 * 1024);
    float* parth2 = alloc(4096 * 512);
    float* parth3 = alloc(4096 * 256);
    float* pre2   = alloc(16777216);  // (B,N,256)

    k_stats1<<<256, 256, 0, stream>>>(pts, w1, b1, part1);
    k_fin<<<64, 256, 0, stream>>>(part1, 256, 128, 64, g1, be1, s1, t1);
    k_lfeat<<<256, 256, 0, stream>>>(pts, w1, b1, s1, t1, lf);
    k_conv3<<<256, 256, 0, stream>>>(lf, w3, b3, part3, y38);
    k_fin<<<512, 256, 0, stream>>>(part3, 1024, 1536, 512, g3, be3, s3, t3);
    k_fin3b<<<16, 512, 0, stream>>>(part3, s3, t3, gmaxb);
    k_a1g1<<<17, 256, 0, stream>>>(hw1, gmaxb, A1, G1);
    k_knn<<<256, 256, 0, stream>>>(pts, y38, s3, t3, mbuf);
    k_h1s<<<256, 256, 0, stream>>>(lf, mbuf, G1, A1, hw1, hb1, parth1);
    k_fin<<<512, 256, 0, stream>>>(parth1, 1024, 1024, 512, hg1, hbe1, sh1, th1);
    k_h2<<<4096, 256, 0, stream>>>(lf, mbuf, G1, A1, hw1, hb1, sh1, th1, hw2, hb2, pre2, parth2);
    k_fin<<<256, 256, 0, stream>>>(parth2, 4096, 512, 256, hg2, hbe2, sh2, th2);
    k_h3s<<<2048, 256, 0, stream>>>(pre2, sh2, th2, hw3, hb3, parth3);
    k_fin<<<128, 256, 0, stream>>>(parth3, 4096, 256, 128, hg3, hbe3, sh3, th3);
    k_h4<<<2048, 256, 0, stream>>>(pre2, sh2, th2, hw3, hb3, sh3, th3, hw4, hb4, (float*)d_out);
}

// Round 2
// 2900.199 us; speedup vs baseline: 1.4420x; 1.4420x over previous
//
#include <hip/hip_runtime.h>
#include <math.h>

// Problem constants
#define BB 16
#define NN 4096
#define NPTS (BB*NN)

#define LEXLT(da,ia,db,ib) (((da) < (db)) || (((da) == (db)) && ((ia) < (ib))))

// ---------------------------------------------------------------------------
// Layer 1 stats: y1 = w1@p + b1 (64 ch), accumulate per-channel sum/sumsq
// grid 256 x 256thr, 1 point/thread
__global__ void k_stats1(const float* __restrict__ pts, const float* __restrict__ w1,
                         const float* __restrict__ b1, float* __restrict__ part1) {
    __shared__ float sw[256];
    __shared__ float wred[2][4][64];
    int t = threadIdx.x;
    if (t < 192) sw[t] = w1[t];
    if (t < 64) sw[192 + t] = b1[t];
    __syncthreads();
    int g = blockIdx.x * 256 + t;
    float p0 = pts[g*3], p1 = pts[g*3+1], p2 = pts[g*3+2];
    int lane = t & 63, wv = t >> 6;
    for (int c = 0; c < 64; c++) {
        float y = fmaf(sw[c*3+2], p2, fmaf(sw[c*3+1], p1, fmaf(sw[c*3], p0, sw[192+c])));
        float s = y, q = y * y;
        #pragma unroll
        for (int o = 32; o > 0; o >>= 1) { s += __shfl_down(s, o); q += __shfl_down(q, o); }
        if (lane == 0) { wred[0][wv][c] = s; wred[1][wv][c] = q; }
    }
    __syncthreads();
    if (t < 64) {
        float s = wred[0][0][t] + wred[0][1][t] + wred[0][2][t] + wred[0][3][t];
        float q = wred[1][0][t] + wred[1][1][t] + wred[1][2][t] + wred[1][3][t];
        part1[blockIdx.x * 128 + t] = s;
        part1[blockIdx.x * 128 + 64 + t] = q;
    }
}

// Generic BN-stat finalize: grid = Cout blocks, 256 thr; computes s,t per channel
__global__ void k_fin(const float* __restrict__ part, int count, int stride, int sqoff,
                      const float* __restrict__ g, const float* __restrict__ be,
                      float* __restrict__ sout, float* __restrict__ tout) {
    int c = blockIdx.x, t = threadIdx.x;
    float s = 0.f, q = 0.f;
    for (int w = t; w < count; w += 256) { s += part[w*stride + c]; q += part[w*stride + sqoff + c]; }
    __shared__ float rs[4], rq[4];
    int lane = t & 63, wv = t >> 6;
    #pragma unroll
    for (int o = 32; o > 0; o >>= 1) { s += __shfl_down(s, o); q += __shfl_down(q, o); }
    if (lane == 0) { rs[wv] = s; rq[wv] = q; }
    __syncthreads();
    if (t == 0) {
        s = rs[0] + rs[1] + rs[2] + rs[3];
        q = rq[0] + rq[1] + rq[2] + rq[3];
        float mean = s / 65536.f;
        float var = q / 65536.f - mean * mean;
        float sc = g[c] * rsqrtf(var + 1e-5f);
        sout[c] = sc;
        tout[c] = be[c] - mean * sc;
    }
}

// l_feat = relu(s1*y1 + t1), layout [b][c][n]
__global__ void k_lfeat(const float* __restrict__ pts, const float* __restrict__ w1,
                        const float* __restrict__ b1, const float* __restrict__ s1,
                        const float* __restrict__ t1, float* __restrict__ lf) {
    __shared__ float sw[256], ss[64], st[64];
    int t = threadIdx.x;
    if (t < 192) sw[t] = w1[t];
    if (t < 64) { sw[192+t] = b1[t]; ss[t] = s1[t]; st[t] = t1[t]; }
    __syncthreads();
    int g = blockIdx.x * 256 + t;
    int b = g >> 12, n = g & 4095;
    float p0 = pts[g*3], p1 = pts[g*3+1], p2 = pts[g*3+2];
    for (int c = 0; c < 64; c++) {
        float y = fmaf(sw[c*3+2], p2, fmaf(sw[c*3+1], p1, fmaf(sw[c*3], p0, sw[192+c])));
        lf[((b<<6)+c)*4096 + n] = fmaxf(fmaf(ss[c], y, st[c]), 0.f);
    }
}

// conv3: y3 = w3@l_feat + b3 (512 ch). Stats (sum/sumsq/max per ch) + store ch 0..7 raw.
__global__ void k_conv3(const float* __restrict__ lf, const float* __restrict__ w3,
                        const float* __restrict__ b3, float* __restrict__ part3,
                        float* __restrict__ y38) {
    int t = threadIdx.x, blk = blockIdx.x;
    int g = blk * 256 + t, b = g >> 12, n = g & 4095;
    float lr[64];
    #pragma unroll
    for (int d = 0; d < 64; d++) lr[d] = lf[((b<<6)+d)*4096 + n];
    int lane = t & 63, wv = t >> 6, wg = blk * 4 + wv;
    for (int c = 0; c < 512; c++) {
        float acc = b3[c];
        #pragma unroll
        for (int d = 0; d < 64; d++) acc = fmaf(w3[(c<<6)+d], lr[d], acc);
        float s = acc, q = acc * acc, mx = acc;
        #pragma unroll
        for (int o = 32; o > 0; o >>= 1) {
            s += __shfl_down(s, o); q += __shfl_down(q, o);
            mx = fmaxf(mx, __shfl_down(mx, o));
        }
        if (lane == 0) {
            part3[wg*1536 + c] = s;
            part3[wg*1536 + 512 + c] = q;
            part3[wg*1536 + 1024 + c] = mx;
        }
        if (c < 8) y38[((b<<3)+c)*4096 + n] = acc;
    }
}

// gmax[b,c] = relu(s3*max_n(y3) + t3)   (s3>0 since g3~1)
__global__ void k_fin3b(const float* __restrict__ part3, const float* __restrict__ s3,
                        const float* __restrict__ t3, float* __restrict__ gmaxb) {
    int b = blockIdx.x, c = threadIdx.x;  // 16 x 512
    float mx = -__builtin_inff();
    for (int w = 0; w < 64; w++) mx = fmaxf(mx, part3[((b<<6)+w)*1536 + 1024 + c]);
    gmaxb[(b<<9)+c] = fmaxf(fmaf(s3[c], mx, t3[c]), 0.f);
}

// A1[o] = sum_{c<512} hw1[o,c];  G1[b,o] = sum_c hw1[o,576+c]*gmax[b,c]
__global__ void k_a1g1(const float* __restrict__ hw1, const float* __restrict__ gmaxb,
                       float* __restrict__ A1, float* __restrict__ G1) {
    int blk = blockIdx.x, t = threadIdx.x;
    if (blk == 16) {
        for (int o = t; o < 512; o += 256) {
            float s = 0.f;
            for (int c = 0; c < 512; c++) s += hw1[o*1088 + c];
            A1[o] = s;
        }
    } else {
        int b = blk;
        for (int o = t; o < 512; o += 256) {
            float s = 0.f;
            for (int c = 0; c < 512; c++) s = fmaf(hw1[o*1088 + 576 + c], gmaxb[(b<<9)+c], s);
            G1[(b<<9)+o] = s;
        }
    }
}

// KNN v2: 8-way candidate split per query, branchless lex insert, windowed staging.
// grid 2048 (16 batches x 128 query-groups of 32) x 256 thr.
// thread: query n = qg*32 + (t>>3), chunk c = t&7 processes candidates == c (mod 8).
__global__ __launch_bounds__(256, 6)
void k_knn(const float* __restrict__ pts, const float* __restrict__ y38,
           const float* __restrict__ s3, const float* __restrict__ t3,
           float* __restrict__ mbuf) {
    __shared__ float4 sp[512];
    int t = threadIdx.x, blk = blockIdx.x;
    int b = blk >> 7;
    int n = (blk & 127) * 32 + (t >> 3);
    int c = t & 7;
    const float* pb = pts + (size_t)b * 4096 * 3;
    float q0 = pb[n*3], q1 = pb[n*3+1], q2 = pb[n*3+2];
    float qx2 = __fadd_rn(__fadd_rn(__fmul_rn(q0,q0), __fmul_rn(q1,q1)), __fmul_rn(q2,q2));
    float kd[8]; int ki[8];
    #pragma unroll
    for (int k = 0; k < 8; k++) { kd[k] = __builtin_inff(); ki[k] = 0x7fffffff; }
    for (int w = 0; w < 8; w++) {
        __syncthreads();
        for (int i = t; i < 512; i += 256) {
            int m = w*512 + i;
            float c0 = pb[m*3], c1 = pb[m*3+1], c2 = pb[m*3+2];
            float cw = __fadd_rn(__fadd_rn(__fmul_rn(c0,c0), __fmul_rn(c1,c1)), __fmul_rn(c2,c2));
            sp[i] = make_float4(c0, c1, c2, cw);
        }
        __syncthreads();
        for (int j = 0; j < 64; j++) {
            float4 cp = sp[j*8 + c];
            int m = w*512 + j*8 + c;
            float dot = __fadd_rn(__fadd_rn(__fmul_rn(q0,cp.x), __fmul_rn(q1,cp.y)), __fmul_rn(q2,cp.z));
            float d = __fsub_rn(__fadd_rn(qx2, cp.w), __fmul_rn(2.f, dot));
            // branchless sorted insert, lexicographic (d, m)
            bool hit = LEXLT(d, m, kd[7], ki[7]);
            kd[7] = hit ? d : kd[7];
            ki[7] = hit ? m : ki[7];
            #pragma unroll
            for (int j2 = 7; j2 > 0; j2--) {
                bool sw = LEXLT(kd[j2], ki[j2], kd[j2-1], ki[j2-1]);
                float dlo = sw ? kd[j2] : kd[j2-1]; float dhi = sw ? kd[j2-1] : kd[j2];
                int   ilo = sw ? ki[j2] : ki[j2-1]; int   ihi = sw ? ki[j2-1] : ki[j2];
                kd[j2-1] = dlo; kd[j2] = dhi; ki[j2-1] = ilo; ki[j2] = ihi;
            }
        }
    }
    // merge 8 sorted partial top-8 lists across the 8 lanes of this query group
    #pragma unroll
    for (int st = 1; st <= 4; st <<= 1) {
        float nd[8]; int ni[8];
        #pragma unroll
        for (int k = 0; k < 8; k++) {
            float pd = __shfl_xor(kd[7-k], st);
            int   pi = __shfl_xor(ki[7-k], st);
            bool take = LEXLT(pd, pi, kd[k], ki[k]);
            nd[k] = take ? pd : kd[k];
            ni[k] = take ? pi : ki[k];
        }
        // nd/ni is bitonic; sort ascending: compare-exchange strides 4, 2, 1
        #define CASM(k1,k2) { bool sw_ = LEXLT(nd[k2], ni[k2], nd[k1], ni[k1]); \
            float tdl_ = sw_ ? nd[k2] : nd[k1]; float tdh_ = sw_ ? nd[k1] : nd[k2]; \
            int   til_ = sw_ ? ni[k2] : ni[k1]; int   tih_ = sw_ ? ni[k1] : ni[k2]; \
            nd[k1] = tdl_; nd[k2] = tdh_; ni[k1] = til_; ni[k2] = tih_; }
        CASM(0,4) CASM(1,5) CASM(2,6) CASM(3,7)
        CASM(0,2) CASM(1,3) CASM(4,6) CASM(5,7)
        CASM(0,1) CASM(2,3) CASM(4,5) CASM(6,7)
        #undef CASM
        #pragma unroll
        for (int k = 0; k < 8; k++) { kd[k] = nd[k]; ki[k] = ni[k]; }
    }
    // m[b,n] = max_k relu(s3[k]*y3[k, idx_k] + t3[k]); lane c handles k = c
    float y = y38[((b<<3)+c)*4096 + ki[c]];
    float mv = fmaxf(fmaf(s3[c], y, t3[c]), 0.f);
    #pragma unroll
    for (int st = 1; st <= 4; st <<= 1) mv = fmaxf(mv, __shfl_xor(mv, st));
    if (c == 0) mbuf[(b<<12)+n] = mv;
}

// h1 stats: pre1[o] = A1[o]*m + hw1[o,512:576]@lf + G1[b,o] + hb1[o]; sum/sumsq per ch
__global__ void k_h1s(const float* __restrict__ lf, const float* __restrict__ mbuf,
                      const float* __restrict__ G1, const float* __restrict__ A1,
                      const float* __restrict__ hw1, const float* __restrict__ hb1,
                      float* __restrict__ parth1) {
    int t = threadIdx.x, blk = blockIdx.x;
    int g = blk * 256 + t, b = g >> 12, n = g & 4095;
    float lr[64];
    #pragma unroll
    for (int d = 0; d < 64; d++) lr[d] = lf[((b<<6)+d)*4096 + n];
    float mval = mbuf[g];
    int lane = t & 63, wv = t >> 6, wg = blk * 4 + wv;
    for (int o = 0; o < 512; o++) {
        float acc = fmaf(A1[o], mval, hb1[o] + G1[(b<<9)+o]);
        #pragma unroll
        for (int d = 0; d < 64; d++) acc = fmaf(hw1[o*1088 + 512 + d], lr[d], acc);
        float s = acc, q = acc * acc;
        #pragma unroll
        for (int off = 32; off > 0; off >>= 1) { s += __shfl_down(s, off); q += __shfl_down(q, off); }
        if (lane == 0) { parth1[wg*1024 + o] = s; parth1[wg*1024 + 512 + o] = q; }
    }
}

// h2: recompute pre1 -> a1 (LDS) -> pre2 = hw2@a1 + hb2; store pre2 [b][n][c] + stats
__global__ void k_h2(const float* __restrict__ lf, const float* __restrict__ mbuf,
                     const float* __restrict__ G1, const float* __restrict__ A1,
                     const float* __restrict__ hw1, const float* __restrict__ hb1,
                     const float* __restrict__ sh1, const float* __restrict__ th1,
                     const float* __restrict__ hw2, const float* __restrict__ hb2,
                     float* __restrict__ pre2, float* __restrict__ parth2) {
    __shared__ float lft[16 * 68];
    __shared__ float a1t[16 * 516];
    __shared__ float sm[16];
    int t = threadIdx.x, blk = blockIdx.x;
    int b = blk >> 8, n0 = (blk & 255) * 16;
    for (int i = t; i < 16 * 64; i += 256) {
        int p = i & 15, d = i >> 4;
        lft[p*68 + d] = lf[((b<<6)+d)*4096 + n0 + p];
    }
    if (t < 16) sm[t] = mbuf[(b<<12) + n0 + t];
    __syncthreads();
    for (int oi = 0; oi < 2; oi++) {
        int o = t + oi * 256;
        float base = hb1[o] + G1[(b<<9)+o];
        float a1c = A1[o];
        float wr[64];
        #pragma unroll
        for (int d4 = 0; d4 < 16; d4++) {
            float4 w = *(const float4*)&hw1[o*1088 + 512 + d4*4];
            wr[d4*4] = w.x; wr[d4*4+1] = w.y; wr[d4*4+2] = w.z; wr[d4*4+3] = w.w;
        }
        float s = sh1[o], tt = th1[o];
        for (int p = 0; p < 16; p++) {
            float acc = fmaf(a1c, sm[p], base);
            #pragma unroll
            for (int d4 = 0; d4 < 16; d4++) {
                float4 v = *(const float4*)&lft[p*68 + d4*4];
                acc = fmaf(wr[d4*4],   v.x, acc);
                acc = fmaf(wr[d4*4+1], v.y, acc);
                acc = fmaf(wr[d4*4+2], v.z, acc);
                acc = fmaf(wr[d4*4+3], v.w, acc);
            }
            a1t[p*516 + o] = fmaxf(fmaf(s, acc, tt), 0.f);
        }
    }
    __syncthreads();
    int c = t;
    float acc[16];
    float hb = hb2[c];
    #pragma unroll
    for (int p = 0; p < 16; p++) acc[p] = hb;
    for (int d4 = 0; d4 < 128; d4++) {
        float4 w = *(const float4*)&hw2[(c<<9) + d4*4];
        #pragma unroll
        for (int p = 0; p < 16; p++) {
            float4 v = *(const float4*)&a1t[p*516 + d4*4];
            acc[p] = fmaf(w.x, v.x, acc[p]);
            acc[p] = fmaf(w.y, v.y, acc[p]);
            acc[p] = fmaf(w.z, v.z, acc[p]);
            acc[p] = fmaf(w.w, v.w, acc[p]);
        }
    }
    float ssum = 0.f, ssq = 0.f;
    #pragma unroll
    for (int p = 0; p < 16; p++) {
        float v = acc[p];
        ssum += v; ssq = fmaf(v, v, ssq);
        pre2[(size_t)(((b<<12) + n0 + p) << 8) + c] = v;
    }
    parth2[blk*512 + c] = ssum;
    parth2[blk*512 + 256 + c] = ssq;
}

// h3 stats pass: a2 = relu(sh2*pre2+th2); pre3 = hw3@a2 + hb3; sum/sumsq per ch
__global__ void k_h3s(const float* __restrict__ pre2, const float* __restrict__ sh2,
                      const float* __restrict__ th2, const float* __restrict__ hw3,
                      const float* __restrict__ hb3, float* __restrict__ parth3) {
    __shared__ float a2t[32 * 260];
    __shared__ float ss[256], st2[256];
    int t = threadIdx.x, blk = blockIdx.x;
    int b = blk >> 7, n0 = (blk & 127) * 32;
    ss[t] = sh2[t]; st2[t] = th2[t];
    __syncthreads();
    for (int i = t; i < 32 * 256; i += 256) {
        int c = i & 255, p = i >> 8;
        float v = pre2[(size_t)(((b<<12) + n0 + p) << 8) + c];
        a2t[p*260 + c] = fmaxf(fmaf(ss[c], v, st2[c]), 0.f);
    }
    __syncthreads();
    int c = t & 127, ph = t >> 7;
    float acc[16];
    float hb = hb3[c];
    #pragma unroll
    for (int p = 0; p < 16; p++) acc[p] = hb;
    for (int d4 = 0; d4 < 64; d4++) {
        float4 w = *(const float4*)&hw3[(c<<8) + d4*4];
        #pragma unroll
        for (int p = 0; p < 16; p++) {
            float4 v = *(const float4*)&a2t[(ph*16 + p)*260 + d4*4];
            acc[p] = fmaf(w.x, v.x, acc[p]);
            acc[p] = fmaf(w.y, v.y, acc[p]);
            acc[p] = fmaf(w.z, v.z, acc[p]);
            acc[p] = fmaf(w.w, v.w, acc[p]);
        }
    }
    float s = 0.f, q = 0.f;
    #pragma unroll
    for (int p = 0; p < 16; p++) { s += acc[p]; q = fmaf(acc[p], acc[p], q); }
    parth3[(blk*2 + ph)*256 + c] = s;
    parth3[(blk*2 + ph)*256 + 128 + c] = q;
}

// h4: recompute pre3 -> a3 (LDS) -> out = hw4@a3 + hb4, write (B,N,6)
__global__ void k_h4(const float* __restrict__ pre2, const float* __restrict__ sh2,
                     const float* __restrict__ th2, const float* __restrict__ hw3,
                     const float* __restrict__ hb3, const float* __restrict__ sh3,
                     const float* __restrict__ th3, const float* __restrict__ hw4,
                     const float* __restrict__ hb4, float* __restrict__ out) {
    __shared__ float a2t[32 * 260];
    __shared__ float a3t[32 * 132];
    __shared__ float ss[256], st2[256];
    int t = threadIdx.x, blk = blockIdx.x;
    int b = blk >> 7, n0 = (blk & 127) * 32;
    ss[t] = sh2[t]; st2[t] = th2[t];
    __syncthreads();
    for (int i = t; i < 32 * 256; i += 256) {
        int c = i & 255, p = i >> 8;
        float v = pre2[(size_t)(((b<<12) + n0 + p) << 8) + c];
        a2t[p*260 + c] = fmaxf(fmaf(ss[c], v, st2[c]), 0.f);
    }
    __syncthreads();
    int c = t & 127, ph = t >> 7;
    float acc[16];
    float hb = hb3[c];
    #pragma unroll
    for (int p = 0; p < 16; p++) acc[p] = hb;
    for (int d4 = 0; d4 < 64; d4++) {
        float4 w = *(const float4*)&hw3[(c<<8) + d4*4];
        #pragma unroll
        for (int p = 0; p < 16; p++) {
            float4 v = *(const float4*)&a2t[(ph*16 + p)*260 + d4*4];
            acc[p] = fmaf(w.x, v.x, acc[p]);
            acc[p] = fmaf(w.y, v.y, acc[p]);
            acc[p] = fmaf(w.z, v.z, acc[p]);
            acc[p] = fmaf(w.w, v.w, acc[p]);
        }
    }
    float s3v = sh3[c], t3v = th3[c];
    #pragma unroll
    for (int p = 0; p < 16; p++)
        a3t[(ph*16 + p)*132 + c] = fmaxf(fmaf(s3v, acc[p], t3v), 0.f);
    __syncthreads();
    int p = t >> 3, cc = t & 7;
    if (cc < 6) {
        float a = hb4[cc];
        for (int d4 = 0; d4 < 32; d4++) {
            float4 w = *(const float4*)&hw4[(cc<<7) + d4*4];
            float4 v = *(const float4*)&a3t[p*132 + d4*4];
            a = fmaf(w.x, v.x, a); a = fmaf(w.y, v.y, a);
            a = fmaf(w.z, v.z, a); a = fmaf(w.w, v.w, a);
        }
        out[(size_t)((b<<12) + n0 + p)*6 + cc] = a;
    }
}

extern "C" void kernel_launch(void* const* d_in, const int* in_sizes, int n_in,
                              void* d_out, int out_size, void* d_ws, size_t ws_size,
                              hipStream_t stream) {
    const float* pts  = (const float*)d_in[0];
    const float* w1   = (const float*)d_in[1];
    const float* b1   = (const float*)d_in[2];
    const float* g1   = (const float*)d_in[3];
    const float* be1  = (const float*)d_in[4];
    const float* w3   = (const float*)d_in[5];
    const float* b3   = (const float*)d_in[6];
    const float* g3   = (const float*)d_in[7];
    const float* be3  = (const float*)d_in[8];
    const float* hw1  = (const float*)d_in[9];
    const float* hb1  = (const float*)d_in[10];
    const float* hg1  = (const float*)d_in[11];
    const float* hbe1 = (const float*)d_in[12];
    const float* hw2  = (const float*)d_in[13];
    const float* hb2  = (const float*)d_in[14];
    const float* hg2  = (const float*)d_in[15];
    const float* hbe2 = (const float*)d_in[16];
    const float* hw3  = (const float*)d_in[17];
    const float* hb3  = (const float*)d_in[18];
    const float* hg3  = (const float*)d_in[19];
    const float* hbe3 = (const float*)d_in[20];
    const float* hw4  = (const float*)d_in[21];
    const float* hb4  = (const float*)d_in[22];
    (void)in_sizes; (void)n_in; (void)out_size; (void)ws_size;

    float* W = (float*)d_ws;
    size_t off = 0;
    auto alloc = [&](size_t n) { float* p = W + off; off += n; return p; };
    float* lf     = alloc(4194304);   // l_feat (B,64,N)
    float* y38    = alloc(524288);    // y3 raw, ch 0..7 (B,8,N)
    float* mbuf   = alloc(65536);     // m[b,n]
    float* gmaxb  = alloc(8192);      // gmax[b,c]
    float* G1     = alloc(8192);
    float* A1     = alloc(512);
    float* s1 = alloc(64);  float* t1 = alloc(64);
    float* s3 = alloc(512); float* t3 = alloc(512);
    float* sh1 = alloc(512); float* th1 = alloc(512);
    float* sh2 = alloc(256); float* th2 = alloc(256);
    float* sh3 = alloc(128); float* th3 = alloc(128);
    float* part1  = alloc(256 * 128);
    float* part3  = alloc(1024 * 1536);
    float* parth1 = alloc(1024 * 1024);
    float* parth2 = alloc(4096 * 512);
    float* parth3 = alloc(4096 * 256);
    float* pre2   = alloc(16777216);  // (B,N,256)

    k_stats1<<<256, 256, 0, stream>>>(pts, w1, b1, part1);
    k_fin<<<64, 256, 0, stream>>>(part1, 256, 128, 64, g1, be1, s1, t1);
    k_lfeat<<<256, 256, 0, stream>>>(pts, w1, b1, s1, t1, lf);
    k_conv3<<<256, 256, 0, stream>>>(lf, w3, b3, part3, y38);
    k_fin<<<512, 256, 0, stream>>>(part3, 1024, 1536, 512, g3, be3, s3, t3);
    k_fin3b<<<16, 512, 0, stream>>>(part3, s3, t3, gmaxb);
    k_a1g1<<<17, 256, 0, stream>>>(hw1, gmaxb, A1, G1);
    k_knn<<<2048, 256, 0, stream>>>(pts, y38, s3, t3, mbuf);
    k_h1s<<<256, 256, 0, stream>>>(lf, mbuf, G1, A1, hw1, hb1, parth1);
    k_fin<<<512, 256, 0, stream>>>(parth1, 1024, 1024, 512, hg1, hbe1, sh1, th1);
    k_h2<<<4096, 256, 0, stream>>>(lf, mbuf, G1, A1, hw1, hb1, sh1, th1, hw2, hb2, pre2, parth2);
    k_fin<<<256, 256, 0, stream>>>(parth2, 4096, 512, 256, hg2, hbe2, sh2, th2);
    k_h3s<<<2048, 256, 0, stream>>>(pre2, sh2, th2, hw3, hb3, parth3);
    k_fin<<<128, 256, 0, stream>>>(parth3, 4096, 256, 128, hg3, hbe3, sh3, th3);
    k_h4<<<2048, 256, 0, stream>>>(pre2, sh2, th2, hw3, hb3, sh3, th3, hw4, hb4, (float*)d_out);
}

// Round 3
// 1055.768 us; speedup vs baseline: 3.9613x; 2.7470x over previous
//
#include <hip/hip_runtime.h>
#include <hip/hip_bf16.h>
#include <math.h>

#define LEXLT(da,ia,db,ib) (((da) < (db)) || (((da) == (db)) && ((ia) < (ib))))

typedef __attribute__((ext_vector_type(8))) short short8;
typedef __attribute__((ext_vector_type(16))) float f32x16;

__device__ inline f32x16 mfma32(short8 a, short8 b, f32x16 c) {
    return __builtin_amdgcn_mfma_f32_32x32x16_bf16(a, b, c, 0, 0, 0);
}

__device__ inline void bsplit(float x, ushort& h, ushort& l) {
    __hip_bfloat16 bh = __float2bfloat16(x);
    float hf = __bfloat162float(bh);
    __hip_bfloat16 bl = __float2bfloat16(x - hf);
    h = *reinterpret_cast<ushort*>(&bh);
    l = *reinterpret_cast<ushort*>(&bl);
}

// ---------------------------------------------------------------------------
// Weight convert: W[o][k] (strided src) -> hi/lo ushort planes [Mdst][K]
__global__ void k_wsplit(const float* __restrict__ src, int rowStride, int colOff,
                         int Msrc, int K, ushort* __restrict__ hi,
                         ushort* __restrict__ lo, int Mdst) {
    int i = blockIdx.x * 256 + threadIdx.x;
    if (i >= Mdst * K) return;
    int o = i / K, k = i - o * K;
    float x = (o < Msrc) ? src[(size_t)o * rowStride + colOff + k] : 0.f;
    ushort h, l;
    bsplit(x, h, l);
    hi[i] = h; lo[i] = l;
}

// ---------------------------------------------------------------------------
// Layer 1 stats
__global__ void k_stats1(const float* __restrict__ pts, const float* __restrict__ w1,
                         const float* __restrict__ b1, float* __restrict__ part1) {
    __shared__ float sw[256];
    __shared__ float wred[2][4][64];
    int t = threadIdx.x;
    if (t < 192) sw[t] = w1[t];
    if (t < 64) sw[192 + t] = b1[t];
    __syncthreads();
    int g = blockIdx.x * 256 + t;
    float p0 = pts[g*3], p1 = pts[g*3+1], p2 = pts[g*3+2];
    int lane = t & 63, wv = t >> 6;
    for (int c = 0; c < 64; c++) {
        float y = fmaf(sw[c*3+2], p2, fmaf(sw[c*3+1], p1, fmaf(sw[c*3], p0, sw[192+c])));
        float s = y, q = y * y;
        #pragma unroll
        for (int o = 32; o > 0; o >>= 1) { s += __shfl_down(s, o); q += __shfl_down(q, o); }
        if (lane == 0) { wred[0][wv][c] = s; wred[1][wv][c] = q; }
    }
    __syncthreads();
    if (t < 64) {
        float s = wred[0][0][t] + wred[0][1][t] + wred[0][2][t] + wred[0][3][t];
        float q = wred[1][0][t] + wred[1][1][t] + wred[1][2][t] + wred[1][3][t];
        part1[blockIdx.x * 128 + t] = s;
        part1[blockIdx.x * 128 + 64 + t] = q;
    }
}

// Generic BN-stat finalize
__global__ void k_fin(const float* __restrict__ part, int count, int stride, int sqoff,
                      const float* __restrict__ g, const float* __restrict__ be,
                      float* __restrict__ sout, float* __restrict__ tout) {
    int c = blockIdx.x, t = threadIdx.x;
    float s = 0.f, q = 0.f;
    for (int w = t; w < count; w += 256) { s += part[(size_t)w*stride + c]; q += part[(size_t)w*stride + sqoff + c]; }
    __shared__ float rs[4], rq[4];
    int lane = t & 63, wv = t >> 6;
    #pragma unroll
    for (int o = 32; o > 0; o >>= 1) { s += __shfl_down(s, o); q += __shfl_down(q, o); }
    if (lane == 0) { rs[wv] = s; rq[wv] = q; }
    __syncthreads();
    if (t == 0) {
        s = rs[0] + rs[1] + rs[2] + rs[3];
        q = rq[0] + rq[1] + rq[2] + rq[3];
        float mean = s / 65536.f;
        float var = q / 65536.f - mean * mean;
        float sc = g[c] * rsqrtf(var + 1e-5f);
        sout[c] = sc;
        tout[c] = be[c] - mean * sc;
    }
}

// l_feat bf16 hi/lo planes, layout [n][64]
__global__ void k_lfeat2(const float* __restrict__ pts, const float* __restrict__ w1,
                         const float* __restrict__ b1, const float* __restrict__ s1,
                         const float* __restrict__ t1, ushort* __restrict__ lfh,
                         ushort* __restrict__ lfl) {
    __shared__ float sw[256], ss[64], st[64];
    int t = threadIdx.x;
    if (t < 192) sw[t] = w1[t];
    if (t < 64) { sw[192+t] = b1[t]; ss[t] = s1[t]; st[t] = t1[t]; }
    __syncthreads();
    int g = blockIdx.x * 256 + t;
    float p0 = pts[g*3], p1 = pts[g*3+1], p2 = pts[g*3+2];
    for (int c0 = 0; c0 < 64; c0 += 8) {
        union { short8 v; ushort u[8]; } H, L;
        #pragma unroll
        for (int j = 0; j < 8; j++) {
            int c = c0 + j;
            float y = fmaf(sw[c*3+2], p2, fmaf(sw[c*3+1], p1, fmaf(sw[c*3], p0, sw[192+c])));
            float a = fmaxf(fmaf(ss[c], y, st[c]), 0.f);
            bsplit(a, H.u[j], L.u[j]);
        }
        *(short8*)(lfh + (size_t)g*64 + c0) = H.v;
        *(short8*)(lfl + (size_t)g*64 + c0) = L.v;
    }
}

// ---------------------------------------------------------------------------
// K=64 MFMA GEMM: MODE 0 = conv3 (stats s/q/max + y38), MODE 1 = h1 stats
// block: 128 pts x 512 ch, 4 waves (wave = 128 ch). B staged in LDS (swm=7).
template<int MODE>
__global__ __launch_bounds__(256, 2) void k_gemm64(
    const ushort* __restrict__ Bhi, const ushort* __restrict__ Blo,
    const ushort* __restrict__ Ahi, const ushort* __restrict__ Alo,
    const float* __restrict__ bias, const float* __restrict__ A1,
    const float* __restrict__ G1, const float* __restrict__ mb,
    float* __restrict__ part, float* __restrict__ y38) {
    __shared__ ushort sbh[128*64], sbl[128*64];
    __shared__ float sPb[512], sPa[512];
    int t = threadIdx.x, pb = blockIdx.x;
    int gn0 = pb * 128, b = pb >> 5;
    for (int i = t; i < 512; i += 256) {
        float bb = bias[i];
        if (MODE) bb += G1[(b<<9) + i];
        sPb[i] = bb;
        sPa[i] = MODE ? A1[i] : 0.f;
    }
    // stage B: rowB=128B, spr=8, 1024 slots per plane
    for (int it = 0; it < 4; it++) {
        int s = it*256 + t;
        int n = s >> 3, c16 = s & 7;
        int off = (c16*16) ^ ((n & 7) << 4);
        int sb8 = (it*256 + (t & 192)) * 8;
        __builtin_amdgcn_global_load_lds((const char*)Bhi + (size_t)(gn0+n)*128 + off, &sbh[sb8], 16, 0, 0);
        __builtin_amdgcn_global_load_lds((const char*)Blo + (size_t)(gn0+n)*128 + off, &sbl[sb8], 16, 0, 0);
    }
    __syncthreads();
    int lane = t & 63, wv = t >> 6, m = lane & 31, kg = lane >> 5;
    for (int ct = 0; ct < 4; ct++) {
        int ch0 = wv*128 + ct*32;
        short8 ah[4], al[4];
        #pragma unroll
        for (int ks = 0; ks < 4; ks++) {
            ah[ks] = *(const short8*)(Ahi + (size_t)(ch0+m)*64 + ks*16 + kg*8);
            al[ks] = *(const short8*)(Alo + (size_t)(ch0+m)*64 + ks*16 + kg*8);
        }
        float ssum[16] = {}, ssq[16] = {}, smx[16];
        #pragma unroll
        for (int r = 0; r < 16; r++) smx[r] = -__builtin_inff();
        for (int pt = 0; pt < 4; pt++) {
            int n = pt*32 + m;
            f32x16 acc = {};
            #pragma unroll
            for (int ks = 0; ks < 4; ks++) {
                int off = ((ks*16 + kg*8)*2) ^ ((n & 7) << 4);
                short8 bh = *(const short8*)((const char*)sbh + n*128 + off);
                short8 bl = *(const short8*)((const char*)sbl + n*128 + off);
                acc = mfma32(ah[ks], bh, acc);
                acc = mfma32(ah[ks], bl, acc);
                acc = mfma32(al[ks], bh, acc);
            }
            float mval = MODE ? mb[gn0 + n] : 0.f;
            #pragma unroll
            for (int r = 0; r < 16; r++) {
                int chr = ch0 + (r&3) + 8*(r>>2) + 4*kg;
                float v = acc[r] + sPb[chr] + (MODE ? sPa[chr]*mval : 0.f);
                ssum[r] += v; ssq[r] = fmaf(v, v, ssq[r]);
                if (MODE == 0) {
                    smx[r] = fmaxf(smx[r], v);
                    if (wv == 0 && ct == 0 && r < 4) {
                        int c8 = (r&3) + 4*kg;  // 0..7
                        y38[(size_t)c8*65536 + gn0 + n] = v;
                    }
                }
            }
        }
        #pragma unroll
        for (int r = 0; r < 16; r++) {
            float s = ssum[r], q = ssq[r], x = smx[r];
            #pragma unroll
            for (int o = 16; o > 0; o >>= 1) {
                s += __shfl_xor(s, o); q += __shfl_xor(q, o);
                if (MODE == 0) x = fmaxf(x, __shfl_xor(x, o));
            }
            if (m == 0) {
                int chr = ch0 + (r&3) + 8*(r>>2) + 4*kg;
                if (MODE == 0) {
                    part[(size_t)pb*1536 + chr] = s;
                    part[(size_t)pb*1536 + 512 + chr] = q;
                    part[(size_t)pb*1536 + 1024 + chr] = x;
                } else {
                    part[(size_t)pb*1024 + chr] = s;
                    part[(size_t)pb*1024 + 512 + chr] = q;
                }
            }
        }
    }
}

// gmax[b,c] = relu(s3*max + t3); part3 blocks 32 per batch
__global__ void k_fin3b(const float* __restrict__ part3, const float* __restrict__ s3,
                        const float* __restrict__ t3, float* __restrict__ gmaxb) {
    int b = blockIdx.x, c = threadIdx.x;
    float mx = -__builtin_inff();
    for (int i = 0; i < 32; i++) mx = fmaxf(mx, part3[(size_t)(b*32+i)*1536 + 1024 + c]);
    gmaxb[(b<<9)+c] = fmaxf(fmaf(s3[c], mx, t3[c]), 0.f);
}

__global__ void k_a1g1(const float* __restrict__ hw1, const float* __restrict__ gmaxb,
                       float* __restrict__ A1, float* __restrict__ G1) {
    int blk = blockIdx.x, t = threadIdx.x;
    if (blk == 16) {
        for (int o = t; o < 512; o += 256) {
            float s = 0.f;
            for (int c = 0; c < 512; c++) s += hw1[o*1088 + c];
            A1[o] = s;
        }
    } else {
        int b = blk;
        for (int o = t; o < 512; o += 256) {
            float s = 0.f;
            for (int c = 0; c < 512; c++) s = fmaf(hw1[o*1088 + 576 + c], gmaxb[(b<<9)+c], s);
            G1[(b<<9)+o] = s;
        }
    }
}

// KNN (unchanged from round 2 except y38 layout [8][65536])
__global__ __launch_bounds__(256, 6)
void k_knn(const float* __restrict__ pts, const float* __restrict__ y38,
           const float* __restrict__ s3, const float* __restrict__ t3,
           float* __restrict__ mbuf) {
    __shared__ float4 sp[512];
    int t = threadIdx.x, blk = blockIdx.x;
    int b = blk >> 7;
    int n = (blk & 127) * 32 + (t >> 3);
    int c = t & 7;
    const float* pb = pts + (size_t)b * 4096 * 3;
    float q0 = pb[n*3], q1 = pb[n*3+1], q2 = pb[n*3+2];
    float qx2 = __fadd_rn(__fadd_rn(__fmul_rn(q0,q0), __fmul_rn(q1,q1)), __fmul_rn(q2,q2));
    float kd[8]; int ki[8];
    #pragma unroll
    for (int k = 0; k < 8; k++) { kd[k] = __builtin_inff(); ki[k] = 0x7fffffff; }
    for (int w = 0; w < 8; w++) {
        __syncthreads();
        for (int i = t; i < 512; i += 256) {
            int m = w*512 + i;
            float c0 = pb[m*3], c1 = pb[m*3+1], c2 = pb[m*3+2];
            float cw = __fadd_rn(__fadd_rn(__fmul_rn(c0,c0), __fmul_rn(c1,c1)), __fmul_rn(c2,c2));
            sp[i] = make_float4(c0, c1, c2, cw);
        }
        __syncthreads();
        for (int j = 0; j < 64; j++) {
            float4 cp = sp[j*8 + c];
            int m = w*512 + j*8 + c;
            float dot = __fadd_rn(__fadd_rn(__fmul_rn(q0,cp.x), __fmul_rn(q1,cp.y)), __fmul_rn(q2,cp.z));
            float d = __fsub_rn(__fadd_rn(qx2, cp.w), __fmul_rn(2.f, dot));
            bool hit = LEXLT(d, m, kd[7], ki[7]);
            kd[7] = hit ? d : kd[7];
            ki[7] = hit ? m : ki[7];
            #pragma unroll
            for (int j2 = 7; j2 > 0; j2--) {
                bool sw = LEXLT(kd[j2], ki[j2], kd[j2-1], ki[j2-1]);
                float dlo = sw ? kd[j2] : kd[j2-1]; float dhi = sw ? kd[j2-1] : kd[j2];
                int   ilo = sw ? ki[j2] : ki[j2-1]; int   ihi = sw ? ki[j2-1] : ki[j2];
                kd[j2-1] = dlo; kd[j2] = dhi; ki[j2-1] = ilo; ki[j2] = ihi;
            }
        }
    }
    #pragma unroll
    for (int st = 1; st <= 4; st <<= 1) {
        float nd[8]; int ni[8];
        #pragma unroll
        for (int k = 0; k < 8; k++) {
            float pd = __shfl_xor(kd[7-k], st);
            int   pi = __shfl_xor(ki[7-k], st);
            bool take = LEXLT(pd, pi, kd[k], ki[k]);
            nd[k] = take ? pd : kd[k];
            ni[k] = take ? pi : ki[k];
        }
        #define CASM(k1,k2) { bool sw_ = LEXLT(nd[k2], ni[k2], nd[k1], ni[k1]); \
            float tdl_ = sw_ ? nd[k2] : nd[k1]; float tdh_ = sw_ ? nd[k1] : nd[k2]; \
            int   til_ = sw_ ? ni[k2] : ni[k1]; int   tih_ = sw_ ? ni[k1] : ni[k2]; \
            nd[k1] = tdl_; nd[k2] = tdh_; ni[k1] = til_; ni[k2] = tih_; }
        CASM(0,4) CASM(1,5) CASM(2,6) CASM(3,7)
        CASM(0,2) CASM(1,3) CASM(4,6) CASM(5,7)
        CASM(0,1) CASM(2,3) CASM(4,5) CASM(6,7)
        #undef CASM
        #pragma unroll
        for (int k = 0; k < 8; k++) { kd[k] = nd[k]; ki[k] = ni[k]; }
    }
    float y = y38[(size_t)c*65536 + (b<<12) + ki[c]];
    float mv = fmaxf(fmaf(s3[c], y, t3[c]), 0.f);
    #pragma unroll
    for (int st = 1; st <= 4; st <<= 1) mv = fmaxf(mv, __shfl_xor(mv, st));
    if (c == 0) mbuf[(b<<12)+n] = mv;
}

// ---------------------------------------------------------------------------
// h2: phase1 recompute a1 (512ch) -> LDS bf16 hi/lo; phase2 pre2 = hw2 @ a1.
// block: 32 pts; 4 waves. grid 2048.
__global__ __launch_bounds__(256, 2) void k_h2m(
    const ushort* __restrict__ lfh, const ushort* __restrict__ lfl,
    const ushort* __restrict__ W1hi, const ushort* __restrict__ W1lo,
    const ushort* __restrict__ W2hi, const ushort* __restrict__ W2lo,
    const float* __restrict__ hb1, const float* __restrict__ A1g,
    const float* __restrict__ G1g, const float* __restrict__ mb,
    const float* __restrict__ sh1, const float* __restrict__ th1,
    const float* __restrict__ hb2,
    float* __restrict__ pre2, float* __restrict__ parth2) {
    __shared__ ushort sbh[32*64], sbl[32*64];    // 4+4 KB
    __shared__ ushort a1h[32*512], a1l[32*512];  // 32+32 KB
    __shared__ float sP0[512], sP1[512], sSh[512], sHb2[256];
    int t = threadIdx.x, pb = blockIdx.x;
    int gn0 = pb * 32, b = pb >> 7;
    for (int i = t; i < 512; i += 256) {
        float s = sh1[i];
        sP0[i] = fmaf(s, hb1[i] + G1g[(b<<9)+i], th1[i]);
        sP1[i] = s * A1g[i];
        sSh[i] = s;
    }
    if (t < 256) sHb2[t] = hb2[t];
    // stage lf tile: 256 slots per plane
    {
        int s = t;
        int n = s >> 3, c16 = s & 7;
        int off = (c16*16) ^ ((n & 7) << 4);
        int sb8 = (t & 192) * 8;
        __builtin_amdgcn_global_load_lds((const char*)lfh + (size_t)(gn0+n)*128 + off, &sbh[sb8], 16, 0, 0);
        __builtin_amdgcn_global_load_lds((const char*)lfl + (size_t)(gn0+n)*128 + off, &sbl[sb8], 16, 0, 0);
    }
    __syncthreads();
    int lane = t & 63, wv = t >> 6, m = lane & 31, kg = lane >> 5;
    float mval = mb[gn0 + m];
    // phase 1
    for (int ct = 0; ct < 4; ct++) {
        int ch0 = wv*128 + ct*32;
        f32x16 acc = {};
        #pragma unroll
        for (int ks = 0; ks < 4; ks++) {
            short8 ah = *(const short8*)(W1hi + (size_t)(ch0+m)*64 + ks*16 + kg*8);
            short8 al = *(const short8*)(W1lo + (size_t)(ch0+m)*64 + ks*16 + kg*8);
            int off = ((ks*16 + kg*8)*2) ^ ((m & 7) << 4);
            short8 bh = *(const short8*)((const char*)sbh + m*128 + off);
            short8 bl = *(const short8*)((const char*)sbl + m*128 + off);
            acc = mfma32(ah, bh, acc);
            acc = mfma32(ah, bl, acc);
            acc = mfma32(al, bh, acc);
        }
        #pragma unroll
        for (int q = 0; q < 4; q++) {
            ushort hs[4], ls[4];
            #pragma unroll
            for (int i = 0; i < 4; i++) {
                int r = q*4 + i;
                int chr = ch0 + i + 8*q + 4*kg;
                float a = fmaxf(fmaf(sSh[chr], acc[r], sP0[chr] + sP1[chr]*mval), 0.f);
                bsplit(a, hs[i], ls[i]);
            }
            int chb = ch0 + 8*q + 4*kg;
            int off = (chb*2) ^ ((m & 15) << 4);
            uint2 vh, vl;
            vh.x = (uint)hs[0] | ((uint)hs[1] << 16); vh.y = (uint)hs[2] | ((uint)hs[3] << 16);
            vl.x = (uint)ls[0] | ((uint)ls[1] << 16); vl.y = (uint)ls[2] | ((uint)ls[3] << 16);
            *(uint2*)((char*)a1h + m*1024 + off) = vh;
            *(uint2*)((char*)a1l + m*1024 + off) = vl;
        }
    }
    __syncthreads();
    // phase 2: wave wv -> ch tiles wv*64, wv*64+32
    f32x16 acc0 = {}, acc1 = {};
    for (int ks = 0; ks < 32; ks++) {
        int ko = ks*16 + kg*8;
        int off = (ko*2) ^ ((m & 15) << 4);
        short8 bh = *(const short8*)((const char*)a1h + m*1024 + off);
        short8 bl = *(const short8*)((const char*)a1l + m*1024 + off);
        short8 a0h = *(const short8*)(W2hi + (size_t)(wv*64+m)*512 + ko);
        short8 a0l = *(const short8*)(W2lo + (size_t)(wv*64+m)*512 + ko);
        short8 a1hh = *(const short8*)(W2hi + (size_t)(wv*64+32+m)*512 + ko);
        short8 a1ll = *(const short8*)(W2lo + (size_t)(wv*64+32+m)*512 + ko);
        acc0 = mfma32(a0h, bh, acc0);
        acc1 = mfma32(a1hh, bh, acc1);
        acc0 = mfma32(a0h, bl, acc0);
        acc1 = mfma32(a1hh, bl, acc1);
        acc0 = mfma32(a0l, bh, acc0);
        acc1 = mfma32(a1ll, bh, acc1);
    }
    #pragma unroll
    for (int ti = 0; ti < 2; ti++) {
        int ch0 = wv*64 + ti*32;
        #pragma unroll
        for (int r = 0; r < 16; r++) {
            int chr = ch0 + (r&3) + 8*(r>>2) + 4*kg;
            float v = (ti ? acc1[r] : acc0[r]) + sHb2[chr];
            pre2[(size_t)chr*65536 + gn0 + m] = v;
            float s = v, q = v*v;
            #pragma unroll
            for (int o = 16; o > 0; o >>= 1) { s += __shfl_xor(s, o); q += __shfl_xor(q, o); }
            if (m == 0) {
                parth2[(size_t)pb*512 + chr] = s;
                parth2[(size_t)pb*512 + 256 + chr] = q;
            }
        }
    }
}

// pre2 [256][65536] fp32 -> a2 hi/lo [n][256] (affine+relu+split, 32x32 transpose)
__global__ void k_a2t(const float* __restrict__ pre2, const float* __restrict__ sh2,
                      const float* __restrict__ th2, ushort* __restrict__ a2h,
                      ushort* __restrict__ a2l) {
    __shared__ float tile[32][33];
    int bi = blockIdx.x;
    int n0 = (bi & 2047) * 32, c0 = (bi >> 11) * 32;
    int t = threadIdx.x;
    int cr = t >> 3, j = (t & 7) * 4;
    float4 v = *(const float4*)(pre2 + (size_t)(c0+cr)*65536 + n0 + j);
    float s = sh2[c0+cr], tt = th2[c0+cr];
    tile[cr][j]   = fmaxf(fmaf(s, v.x, tt), 0.f);
    tile[cr][j+1] = fmaxf(fmaf(s, v.y, tt), 0.f);
    tile[cr][j+2] = fmaxf(fmaf(s, v.z, tt), 0.f);
    tile[cr][j+3] = fmaxf(fmaf(s, v.w, tt), 0.f);
    __syncthreads();
    int nr = t >> 3, cj = (t & 7) * 4;
    uint2 vh, vl;
    ushort hs[4], ls[4];
    #pragma unroll
    for (int i = 0; i < 4; i++) bsplit(tile[cj+i][nr], hs[i], ls[i]);
    vh.x = (uint)hs[0] | ((uint)hs[1] << 16); vh.y = (uint)hs[2] | ((uint)hs[3] << 16);
    vl.x = (uint)ls[0] | ((uint)ls[1] << 16); vl.y = (uint)ls[2] | ((uint)ls[3] << 16);
    *(uint2*)(a2h + (size_t)(n0+nr)*256 + c0 + cj) = vh;
    *(uint2*)(a2l + (size_t)(n0+nr)*256 + c0 + cj) = vl;
}

// h3 stats: pre3 = hw3(128x256) @ a2, per-ch sum/sq. block: 128 pts, 4 waves.
__global__ __launch_bounds__(256, 2) void k_h3s(
    const ushort* __restrict__ a2h, const ushort* __restrict__ a2l,
    const ushort* __restrict__ W3hi, const ushort* __restrict__ W3lo,
    const float* __restrict__ hb3, float* __restrict__ parth3) {
    __shared__ ushort sbh[32*256], sbl[32*256];  // 16+16 KB
    int t = threadIdx.x, pb = blockIdx.x;
    int lane = t & 63, wv = t >> 6, m = lane & 31, kg = lane >> 5;
    int ch0 = wv * 32;
    float bhr[16];
    #pragma unroll
    for (int r = 0; r < 16; r++) bhr[r] = hb3[ch0 + (r&3) + 8*(r>>2) + 4*kg];
    float ssum[16] = {}, ssq[16] = {};
    for (int pt = 0; pt < 4; pt++) {
        int gn0 = pb*128 + pt*32;
        __syncthreads();
        for (int it = 0; it < 4; it++) {
            int s = it*256 + t;
            int n = s >> 5, c16 = s & 31;
            int off = (c16*16) ^ ((n & 15) << 4);
            int sb8 = (it*256 + (t & 192)) * 8;
            __builtin_amdgcn_global_load_lds((const char*)a2h + (size_t)(gn0+n)*512 + off, &sbh[sb8], 16, 0, 0);
            __builtin_amdgcn_global_load_lds((const char*)a2l + (size_t)(gn0+n)*512 + off, &sbl[sb8], 16, 0, 0);
        }
        __syncthreads();
        f32x16 acc = {};
        for (int ks = 0; ks < 16; ks++) {
            int ko = ks*16 + kg*8;
            int off = (ko*2) ^ ((m & 15) << 4);
            short8 bh = *(const short8*)((const char*)sbh + m*512 + off);
            short8 bl = *(const short8*)((const char*)sbl + m*512 + off);
            short8 ah = *(const short8*)(W3hi + (size_t)(ch0+m)*256 + ko);
            short8 al = *(const short8*)(W3lo + (size_t)(ch0+m)*256 + ko);
            acc = mfma32(ah, bh, acc);
            acc = mfma32(ah, bl, acc);
            acc = mfma32(al, bh, acc);
        }
        #pragma unroll
        for (int r = 0; r < 16; r++) {
            float v = acc[r] + bhr[r];
            ssum[r] += v; ssq[r] = fmaf(v, v, ssq[r]);
        }
    }
    #pragma unroll
    for (int r = 0; r < 16; r++) {
        float s = ssum[r], q = ssq[r];
        #pragma unroll
        for (int o = 16; o > 0; o >>= 1) { s += __shfl_xor(s, o); q += __shfl_xor(q, o); }
        if (m == 0) {
            int chr = ch0 + (r&3) + 8*(r>>2) + 4*kg;
            parth3[(size_t)pb*256 + chr] = s;
            parth3[(size_t)pb*256 + 128 + chr] = q;
        }
    }
}

// h4: recompute pre3 -> a3 (LDS bf16) -> out = hw4 @ a3. block: 32 pts, 4 waves.
__global__ __launch_bounds__(256, 2) void k_h4m(
    const ushort* __restrict__ a2h, const ushort* __restrict__ a2l,
    const ushort* __restrict__ W3hi, const ushort* __restrict__ W3lo,
    const float* __restrict__ hb3, const float* __restrict__ sh3,
    const float* __restrict__ th3, const ushort* __restrict__ W4hi,
    const ushort* __restrict__ W4lo, const float* __restrict__ hb4,
    float* __restrict__ out) {
    __shared__ ushort sbh[32*256], sbl[32*256];  // 16+16 KB
    __shared__ ushort a3h[32*128], a3l[32*128];  // 8+8 KB
    __shared__ float sS[128], sT[128], sB[128];
    int t = threadIdx.x, pb = blockIdx.x;
    int gn0 = pb * 32;
    if (t < 128) { sS[t] = sh3[t]; sT[t] = th3[t]; sB[t] = hb3[t]; }
    for (int it = 0; it < 4; it++) {
        int s = it*256 + t;
        int n = s >> 5, c16 = s & 31;
        int off = (c16*16) ^ ((n & 15) << 4);
        int sb8 = (it*256 + (t & 192)) * 8;
        __builtin_amdgcn_global_load_lds((const char*)a2h + (size_t)(gn0+n)*512 + off, &sbh[sb8], 16, 0, 0);
        __builtin_amdgcn_global_load_lds((const char*)a2l + (size_t)(gn0+n)*512 + off, &sbl[sb8], 16, 0, 0);
    }
    __syncthreads();
    int lane = t & 63, wv = t >> 6, m = lane & 31, kg = lane >> 5;
    int ch0 = wv * 32;
    f32x16 acc = {};
    for (int ks = 0; ks < 16; ks++) {
        int ko = ks*16 + kg*8;
        int off = (ko*2) ^ ((m & 15) << 4);
        short8 bh = *(const short8*)((const char*)sbh + m*512 + off);
        short8 bl = *(const short8*)((const char*)sbl + m*512 + off);
        short8 ah = *(const short8*)(W3hi + (size_t)(ch0+m)*256 + ko);
        short8 al = *(const short8*)(W3lo + (size_t)(ch0+m)*256 + ko);
        acc = mfma32(ah, bh, acc);
        acc = mfma32(ah, bl, acc);
        acc = mfma32(al, bh, acc);
    }
    #pragma unroll
    for (int q = 0; q < 4; q++) {
        ushort hs[4], ls[4];
        #pragma unroll
        for (int i = 0; i < 4; i++) {
            int r = q*4 + i;
            int chr = ch0 + i + 8*q + 4*kg;
            float v = fmaxf(fmaf(sS[chr], acc[r] + sB[chr], sT[chr]), 0.f);
            bsplit(v, hs[i], ls[i]);
        }
        int chb = ch0 + 8*q + 4*kg;
        int off = (chb*2) ^ ((m & 15) << 4);
        uint2 vh, vl;
        vh.x = (uint)hs[0] | ((uint)hs[1] << 16); vh.y = (uint)hs[2] | ((uint)hs[3] << 16);
        vl.x = (uint)ls[0] | ((uint)ls[1] << 16); vl.y = (uint)ls[2] | ((uint)ls[3] << 16);
        *(uint2*)((char*)a3h + m*256 + off) = vh;
        *(uint2*)((char*)a3l + m*256 + off) = vl;
    }
    __syncthreads();
    if (wv == 0) {
        f32x16 acc2 = {};
        for (int ks = 0; ks < 8; ks++) {
            int ko = ks*16 + kg*8;
            int off = (ko*2) ^ ((m & 15) << 4);
            short8 bh = *(const short8*)((const char*)a3h + m*256 + off);
            short8 bl = *(const short8*)((const char*)a3l + m*256 + off);
            short8 ah = *(const short8*)(W4hi + (size_t)m*128 + ko);
            short8 al = *(const short8*)(W4lo + (size_t)m*128 + ko);
            acc2 = mfma32(ah, bh, acc2);
            acc2 = mfma32(ah, bl, acc2);
            acc2 = mfma32(al, bh, acc2);
        }
        #pragma unroll
        for (int r = 0; r < 16; r++) {
            int mrow = (r&3) + 8*(r>>2) + 4*kg;
            if (mrow < 6) out[(size_t)(gn0+m)*6 + mrow] = acc2[r] + hb4[mrow];
        }
    }
}

extern "C" void kernel_launch(void* const* d_in, const int* in_sizes, int n_in,
                              void* d_out, int out_size, void* d_ws, size_t ws_size,
                              hipStream_t stream) {
    const float* pts  = (const float*)d_in[0];
    const float* w1   = (const float*)d_in[1];
    const float* b1   = (const float*)d_in[2];
    const float* g1   = (const float*)d_in[3];
    const float* be1  = (const float*)d_in[4];
    const float* w3   = (const float*)d_in[5];
    const float* b3   = (const float*)d_in[6];
    const float* g3   = (const float*)d_in[7];
    const float* be3  = (const float*)d_in[8];
    const float* hw1  = (const float*)d_in[9];
    const float* hb1  = (const float*)d_in[10];
    const float* hg1  = (const float*)d_in[11];
    const float* hbe1 = (const float*)d_in[12];
    const float* hw2  = (const float*)d_in[13];
    const float* hb2  = (const float*)d_in[14];
    const float* hg2  = (const float*)d_in[15];
    const float* hbe2 = (const float*)d_in[16];
    const float* hw3  = (const float*)d_in[17];
    const float* hb3  = (const float*)d_in[18];
    const float* hg3  = (const float*)d_in[19];
    const float* hbe3 = (const float*)d_in[20];
    const float* hw4  = (const float*)d_in[21];
    const float* hb4  = (const float*)d_in[22];
    (void)in_sizes; (void)n_in; (void)out_size; (void)ws_size;

    float* W = (float*)d_ws;
    size_t off = 0;
    auto alloc = [&](size_t n) { float* p = W + off; off += n; return p; };
    auto allocU = [&](size_t nshorts) { return (ushort*)alloc((nshorts + 1) / 2); };

    ushort* lfh  = allocU(65536UL*64);
    ushort* lfl  = allocU(65536UL*64);
    ushort* a2h  = allocU(65536UL*256);
    ushort* a2l  = allocU(65536UL*256);
    ushort* w3h  = allocU(512*64);  ushort* w3l  = allocU(512*64);
    ushort* w1eh = allocU(512*64);  ushort* w1el = allocU(512*64);
    ushort* w2h  = allocU(256*512); ushort* w2l  = allocU(256*512);
    ushort* wh3h = allocU(128*256); ushort* wh3l = allocU(128*256);
    ushort* w4h  = allocU(32*128);  ushort* w4l  = allocU(32*128);
    float* y38    = alloc(524288);
    float* mbuf   = alloc(65536);
    float* gmaxb  = alloc(8192);
    float* G1     = alloc(8192);
    float* A1     = alloc(512);
    float* s1 = alloc(64);  float* t1 = alloc(64);
    float* s3 = alloc(512); float* t3 = alloc(512);
    float* sh1 = alloc(512); float* th1 = alloc(512);
    float* sh2 = alloc(256); float* th2 = alloc(256);
    float* sh3 = alloc(128); float* th3 = alloc(128);
    float* part1  = alloc(32768);
    float* part3  = alloc(512*1536);
    float* parth1 = alloc(512*1024);
    float* parth2 = alloc(2048*512);
    float* parth3 = alloc(512*256);
    float* pre2   = alloc(16777216);

    // weight conversions
    k_wsplit<<<128, 256, 0, stream>>>(w3, 64, 0, 512, 64, w3h, w3l, 512);
    k_wsplit<<<128, 256, 0, stream>>>(hw1, 1088, 512, 512, 64, w1eh, w1el, 512);
    k_wsplit<<<512, 256, 0, stream>>>(hw2, 512, 0, 256, 512, w2h, w2l, 256);
    k_wsplit<<<128, 256, 0, stream>>>(hw3, 256, 0, 128, 256, wh3h, wh3l, 128);
    k_wsplit<<<16, 256, 0, stream>>>(hw4, 128, 0, 6, 128, w4h, w4l, 32);

    k_stats1<<<256, 256, 0, stream>>>(pts, w1, b1, part1);
    k_fin<<<64, 256, 0, stream>>>(part1, 256, 128, 64, g1, be1, s1, t1);
    k_lfeat2<<<256, 256, 0, stream>>>(pts, w1, b1, s1, t1, lfh, lfl);
    k_gemm64<0><<<512, 256, 0, stream>>>(lfh, lfl, w3h, w3l, b3, nullptr, nullptr, nullptr, part3, y38);
    k_fin<<<512, 256, 0, stream>>>(part3, 512, 1536, 512, g3, be3, s3, t3);
    k_fin3b<<<16, 512, 0, stream>>>(part3, s3, t3, gmaxb);
    k_a1g1<<<17, 256, 0, stream>>>(hw1, gmaxb, A1, G1);
    k_knn<<<2048, 256, 0, stream>>>(pts, y38, s3, t3, mbuf);
    k_gemm64<1><<<512, 256, 0, stream>>>(lfh, lfl, w1eh, w1el, hb1, A1, G1, mbuf, parth1, nullptr);
    k_fin<<<512, 256, 0, stream>>>(parth1, 512, 1024, 512, hg1, hbe1, sh1, th1);
    k_h2m<<<2048, 256, 0, stream>>>(lfh, lfl, w1eh, w1el, w2h, w2l, hb1, A1, G1, mbuf,
                                    sh1, th1, hb2, pre2, parth2);
    k_fin<<<256, 256, 0, stream>>>(parth2, 2048, 512, 256, hg2, hbe2, sh2, th2);
    k_a2t<<<16384, 256, 0, stream>>>(pre2, sh2, th2, a2h, a2l);
    k_h3s<<<512, 256, 0, stream>>>(a2h, a2l, wh3h, wh3l, hb3, parth3);
    k_fin<<<128, 256, 0, stream>>>(parth3, 512, 256, 128, hg3, hbe3, sh3, th3);
    k_h4m<<<2048, 256, 0, stream>>>(a2h, a2l, wh3h, wh3l, hb3, sh3, th3, w4h, w4l, hb4, (float*)d_out);
}

// Round 4
// 850.822 us; speedup vs baseline: 4.9155x; 1.2409x over previous
//
#include <hip/hip_runtime.h>
#include <hip/hip_bf16.h>
#include <math.h>

#define LEXLT(da,ia,db,ib) (((da) < (db)) || (((da) == (db)) && ((ia) < (ib))))

typedef __attribute__((ext_vector_type(8))) short short8;
typedef __attribute__((ext_vector_type(16))) float f32x16;

__device__ inline f32x16 mfma32(short8 a, short8 b, f32x16 c) {
    return __builtin_amdgcn_mfma_f32_32x32x16_bf16(a, b, c, 0, 0, 0);
}

__device__ inline void bsplit(float x, ushort& h, ushort& l) {
    __hip_bfloat16 bh = __float2bfloat16(x);
    float hf = __bfloat162float(bh);
    __hip_bfloat16 bl = __float2bfloat16(x - hf);
    h = *reinterpret_cast<ushort*>(&bh);
    l = *reinterpret_cast<ushort*>(&bl);
}

// ---------------------------------------------------------------------------
// Weight convert: W[o][k] (strided src) -> hi/lo ushort planes [Mdst][K]
__global__ void k_wsplit(const float* __restrict__ src, int rowStride, int colOff,
                         int Msrc, int K, ushort* __restrict__ hi,
                         ushort* __restrict__ lo, int Mdst) {
    int i = blockIdx.x * 256 + threadIdx.x;
    if (i >= Mdst * K) return;
    int o = i / K, k = i - o * K;
    float x = (o < Msrc) ? src[(size_t)o * rowStride + colOff + k] : 0.f;
    ushort h, l;
    bsplit(x, h, l);
    hi[i] = h; lo[i] = l;
}

// ---------------------------------------------------------------------------
// Layer 1 stats
__global__ void k_stats1(const float* __restrict__ pts, const float* __restrict__ w1,
                         const float* __restrict__ b1, float* __restrict__ part1) {
    __shared__ float sw[256];
    __shared__ float wred[2][4][64];
    int t = threadIdx.x;
    if (t < 192) sw[t] = w1[t];
    if (t < 64) sw[192 + t] = b1[t];
    __syncthreads();
    int g = blockIdx.x * 256 + t;
    float p0 = pts[g*3], p1 = pts[g*3+1], p2 = pts[g*3+2];
    int lane = t & 63, wv = t >> 6;
    for (int c = 0; c < 64; c++) {
        float y = fmaf(sw[c*3+2], p2, fmaf(sw[c*3+1], p1, fmaf(sw[c*3], p0, sw[192+c])));
        float s = y, q = y * y;
        #pragma unroll
        for (int o = 32; o > 0; o >>= 1) { s += __shfl_down(s, o); q += __shfl_down(q, o); }
        if (lane == 0) { wred[0][wv][c] = s; wred[1][wv][c] = q; }
    }
    __syncthreads();
    if (t < 64) {
        float s = wred[0][0][t] + wred[0][1][t] + wred[0][2][t] + wred[0][3][t];
        float q = wred[1][0][t] + wred[1][1][t] + wred[1][2][t] + wred[1][3][t];
        part1[blockIdx.x * 128 + t] = s;
        part1[blockIdx.x * 128 + 64 + t] = q;
    }
}

// Generic BN-stat finalize
__global__ void k_fin(const float* __restrict__ part, int count, int stride, int sqoff,
                      const float* __restrict__ g, const float* __restrict__ be,
                      float* __restrict__ sout, float* __restrict__ tout) {
    int c = blockIdx.x, t = threadIdx.x;
    float s = 0.f, q = 0.f;
    for (int w = t; w < count; w += 256) { s += part[(size_t)w*stride + c]; q += part[(size_t)w*stride + sqoff + c]; }
    __shared__ float rs[4], rq[4];
    int lane = t & 63, wv = t >> 6;
    #pragma unroll
    for (int o = 32; o > 0; o >>= 1) { s += __shfl_down(s, o); q += __shfl_down(q, o); }
    if (lane == 0) { rs[wv] = s; rq[wv] = q; }
    __syncthreads();
    if (t == 0) {
        s = rs[0] + rs[1] + rs[2] + rs[3];
        q = rq[0] + rq[1] + rq[2] + rq[3];
        float mean = s / 65536.f;
        float var = q / 65536.f - mean * mean;
        float sc = g[c] * rsqrtf(var + 1e-5f);
        sout[c] = sc;
        tout[c] = be[c] - mean * sc;
    }
}

// l_feat bf16 hi/lo planes, layout [n][64]
__global__ void k_lfeat2(const float* __restrict__ pts, const float* __restrict__ w1,
                         const float* __restrict__ b1, const float* __restrict__ s1,
                         const float* __restrict__ t1, ushort* __restrict__ lfh,
                         ushort* __restrict__ lfl) {
    __shared__ float sw[256], ss[64], st[64];
    int t = threadIdx.x;
    if (t < 192) sw[t] = w1[t];
    if (t < 64) { sw[192+t] = b1[t]; ss[t] = s1[t]; st[t] = t1[t]; }
    __syncthreads();
    int g = blockIdx.x * 256 + t;
    float p0 = pts[g*3], p1 = pts[g*3+1], p2 = pts[g*3+2];
    for (int c0 = 0; c0 < 64; c0 += 8) {
        union { short8 v; ushort u[8]; } H, L;
        #pragma unroll
        for (int j = 0; j < 8; j++) {
            int c = c0 + j;
            float y = fmaf(sw[c*3+2], p2, fmaf(sw[c*3+1], p1, fmaf(sw[c*3], p0, sw[192+c])));
            float a = fmaxf(fmaf(ss[c], y, st[c]), 0.f);
            bsplit(a, H.u[j], L.u[j]);
        }
        *(short8*)(lfh + (size_t)g*64 + c0) = H.v;
        *(short8*)(lfl + (size_t)g*64 + c0) = L.v;
    }
}

// ---------------------------------------------------------------------------
// K=64 MFMA GEMM: MODE 0 = conv3 (stats s/q/max + y38), MODE 1 = h1 stats
template<int MODE>
__global__ __launch_bounds__(256, 2) void k_gemm64(
    const ushort* __restrict__ Bhi, const ushort* __restrict__ Blo,
    const ushort* __restrict__ Ahi, const ushort* __restrict__ Alo,
    const float* __restrict__ bias, const float* __restrict__ A1,
    const float* __restrict__ G1, const float* __restrict__ mb,
    float* __restrict__ part, float* __restrict__ y38) {
    __shared__ ushort sbh[128*64], sbl[128*64];
    __shared__ float sPb[512], sPa[512];
    int t = threadIdx.x, pb = blockIdx.x;
    int gn0 = pb * 128, b = pb >> 5;
    for (int i = t; i < 512; i += 256) {
        float bb = bias[i];
        if (MODE) bb += G1[(b<<9) + i];
        sPb[i] = bb;
        sPa[i] = MODE ? A1[i] : 0.f;
    }
    for (int it = 0; it < 4; it++) {
        int s = it*256 + t;
        int n = s >> 3, c16 = s & 7;
        int off = (c16*16) ^ ((n & 7) << 4);
        int sb8 = (it*256 + (t & 192)) * 8;
        __builtin_amdgcn_global_load_lds((const char*)Bhi + (size_t)(gn0+n)*128 + off, &sbh[sb8], 16, 0, 0);
        __builtin_amdgcn_global_load_lds((const char*)Blo + (size_t)(gn0+n)*128 + off, &sbl[sb8], 16, 0, 0);
    }
    __syncthreads();
    int lane = t & 63, wv = t >> 6, m = lane & 31, kg = lane >> 5;
    for (int ct = 0; ct < 4; ct++) {
        int ch0 = wv*128 + ct*32;
        short8 ah[4], al[4];
        #pragma unroll
        for (int ks = 0; ks < 4; ks++) {
            ah[ks] = *(const short8*)(Ahi + (size_t)(ch0+m)*64 + ks*16 + kg*8);
            al[ks] = *(const short8*)(Alo + (size_t)(ch0+m)*64 + ks*16 + kg*8);
        }
        float ssum[16] = {}, ssq[16] = {}, smx[16];
        #pragma unroll
        for (int r = 0; r < 16; r++) smx[r] = -__builtin_inff();
        for (int pt = 0; pt < 4; pt++) {
            int n = pt*32 + m;
            f32x16 acc = {};
            #pragma unroll
            for (int ks = 0; ks < 4; ks++) {
                int off = ((ks*16 + kg*8)*2) ^ ((n & 7) << 4);
                short8 bh = *(const short8*)((const char*)sbh + n*128 + off);
                short8 bl = *(const short8*)((const char*)sbl + n*128 + off);
                acc = mfma32(ah[ks], bh, acc);
                acc = mfma32(ah[ks], bl, acc);
                acc = mfma32(al[ks], bh, acc);
            }
            float mval = MODE ? mb[gn0 + n] : 0.f;
            #pragma unroll
            for (int r = 0; r < 16; r++) {
                int chr = ch0 + (r&3) + 8*(r>>2) + 4*kg;
                float v = acc[r] + sPb[chr] + (MODE ? sPa[chr]*mval : 0.f);
                ssum[r] += v; ssq[r] = fmaf(v, v, ssq[r]);
                if (MODE == 0) {
                    smx[r] = fmaxf(smx[r], v);
                    if (wv == 0 && ct == 0 && r < 4) {
                        int c8 = (r&3) + 4*kg;  // 0..7
                        y38[(size_t)c8*65536 + gn0 + n] = v;
                    }
                }
            }
        }
        #pragma unroll
        for (int r = 0; r < 16; r++) {
            float s = ssum[r], q = ssq[r], x = smx[r];
            #pragma unroll
            for (int o = 16; o > 0; o >>= 1) {
                s += __shfl_xor(s, o); q += __shfl_xor(q, o);
                if (MODE == 0) x = fmaxf(x, __shfl_xor(x, o));
            }
            if (m == 0) {
                int chr = ch0 + (r&3) + 8*(r>>2) + 4*kg;
                if (MODE == 0) {
                    part[(size_t)pb*1536 + chr] = s;
                    part[(size_t)pb*1536 + 512 + chr] = q;
                    part[(size_t)pb*1536 + 1024 + chr] = x;
                } else {
                    part[(size_t)pb*1024 + chr] = s;
                    part[(size_t)pb*1024 + 512 + chr] = q;
                }
            }
        }
    }
}

// gmax[b,c] = relu(s3*max + t3); part3 blocks 32 per batch
__global__ void k_fin3b(const float* __restrict__ part3, const float* __restrict__ s3,
                        const float* __restrict__ t3, float* __restrict__ gmaxb) {
    int b = blockIdx.x, c = threadIdx.x;
    float mx = -__builtin_inff();
    for (int i = 0; i < 32; i++) mx = fmaxf(mx, part3[(size_t)(b*32+i)*1536 + 1024 + c]);
    gmaxb[(b<<9)+c] = fmaxf(fmaf(s3[c], mx, t3[c]), 0.f);
}

__global__ void k_a1g1(const float* __restrict__ hw1, const float* __restrict__ gmaxb,
                       float* __restrict__ A1, float* __restrict__ G1) {
    int blk = blockIdx.x, t = threadIdx.x;
    if (blk == 16) {
        for (int o = t; o < 512; o += 256) {
            float s = 0.f;
            for (int c = 0; c < 512; c++) s += hw1[o*1088 + c];
            A1[o] = s;
        }
    } else {
        int b = blk;
        for (int o = t; o < 512; o += 256) {
            float s = 0.f;
            for (int c = 0; c < 512; c++) s = fmaf(hw1[o*1088 + 576 + c], gmaxb[(b<<9)+c], s);
            G1[(b<<9)+o] = s;
        }
    }
}

// ---------------------------------------------------------------------------
// KNN v3: u64 sortable keys (monotone-mapped fp32 dist | idx).
// 8 lanes/query, branchless u64 insertion; bitonic cross-lane merge.
// Exact fp32 dist arithmetic identical to reference.
__global__ __launch_bounds__(256, 8)
void k_knn(const float* __restrict__ pts, const float* __restrict__ y38,
           const float* __restrict__ s3, const float* __restrict__ t3,
           float* __restrict__ mbuf) {
    __shared__ float4 sp[512];
    int t = threadIdx.x, blk = blockIdx.x;
    int b = blk >> 7;
    int n = (blk & 127) * 32 + (t >> 3);
    int c = t & 7;
    const float* pb = pts + (size_t)b * 4096 * 3;
    float q0 = pb[n*3], q1 = pb[n*3+1], q2 = pb[n*3+2];
    float qx2 = __fadd_rn(__fadd_rn(__fmul_rn(q0,q0), __fmul_rn(q1,q1)), __fmul_rn(q2,q2));
    unsigned long long kd[8];
    #pragma unroll
    for (int k = 0; k < 8; k++) kd[k] = ~0ull;
    for (int w = 0; w < 8; w++) {
        __syncthreads();
        for (int i = t; i < 512; i += 256) {
            int m = w*512 + i;
            float c0 = pb[m*3], c1 = pb[m*3+1], c2 = pb[m*3+2];
            float cw = __fadd_rn(__fadd_rn(__fmul_rn(c0,c0), __fmul_rn(c1,c1)), __fmul_rn(c2,c2));
            sp[i] = make_float4(c0, c1, c2, cw);
        }
        __syncthreads();
        for (int j = 0; j < 64; j++) {
            float4 cp = sp[j*8 + c];
            unsigned int m = (unsigned int)(w*512 + j*8 + c);
            float dot = __fadd_rn(__fadd_rn(__fmul_rn(q0,cp.x), __fmul_rn(q1,cp.y)), __fmul_rn(q2,cp.z));
            float d = __fsub_rn(__fadd_rn(qx2, cp.w), __fmul_rn(2.f, dot));
            unsigned int db = __float_as_uint(d);
            unsigned int mp = db ^ (0x80000000u | (unsigned int)((int)db >> 31));
            unsigned long long key = ((unsigned long long)mp << 32) | m;
            // entry: slot7 = min(slot7, key); then bubble up (strict u64 order)
            kd[7] = (key < kd[7]) ? key : kd[7];
            #pragma unroll
            for (int j2 = 7; j2 > 0; j2--) {
                unsigned long long a = kd[j2-1], bb = kd[j2];
                bool sw = bb < a;
                kd[j2-1] = sw ? bb : a;
                kd[j2]   = sw ? a : bb;
            }
        }
    }
    // merge 8 sorted lists across the 8 lanes of this query group
    #pragma unroll
    for (int st = 1; st <= 4; st <<= 1) {
        unsigned long long nd[8];
        #pragma unroll
        for (int k = 0; k < 8; k++) {
            unsigned long long pd = __shfl_xor(kd[7-k], st);
            nd[k] = (pd < kd[k]) ? pd : kd[k];
        }
        // nd is bitonic; sort ascending: strides 4, 2, 1
        #define CASM(k1,k2) { unsigned long long a_ = nd[k1], b_ = nd[k2]; \
            bool sw_ = b_ < a_; nd[k1] = sw_ ? b_ : a_; nd[k2] = sw_ ? a_ : b_; }
        CASM(0,4) CASM(1,5) CASM(2,6) CASM(3,7)
        CASM(0,2) CASM(1,3) CASM(4,6) CASM(5,7)
        CASM(0,1) CASM(2,3) CASM(4,5) CASM(6,7)
        #undef CASM
        #pragma unroll
        for (int k = 0; k < 8; k++) kd[k] = nd[k];
    }
    // m[b,n] = max_k relu(s3[k]*y3[k, idx_k] + t3[k]); lane c handles k = c
    unsigned int idx = (unsigned int)(kd[c] & 0xffffffffull);
    float y = y38[(size_t)c*65536 + (b<<12) + (idx & 4095)];
    float mv = fmaxf(fmaf(s3[c], y, t3[c]), 0.f);
    #pragma unroll
    for (int st = 1; st <= 4; st <<= 1) mv = fmaxf(mv, __shfl_xor(mv, st));
    if (c == 0) mbuf[(b<<12)+n] = mv;
}

// ---------------------------------------------------------------------------
// h2: phase1 recompute a1 (512ch) -> LDS bf16 hi/lo; phase2 pre2 = hw2 @ a1.
__global__ __launch_bounds__(256, 2) void k_h2m(
    const ushort* __restrict__ lfh, const ushort* __restrict__ lfl,
    const ushort* __restrict__ W1hi, const ushort* __restrict__ W1lo,
    const ushort* __restrict__ W2hi, const ushort* __restrict__ W2lo,
    const float* __restrict__ hb1, const float* __restrict__ A1g,
    const float* __restrict__ G1g, const float* __restrict__ mb,
    const float* __restrict__ sh1, const float* __restrict__ th1,
    const float* __restrict__ hb2,
    float* __restrict__ pre2, float* __restrict__ parth2) {
    __shared__ ushort sbh[32*64], sbl[32*64];    // 4+4 KB
    __shared__ ushort a1h[32*512], a1l[32*512];  // 32+32 KB
    __shared__ float sP0[512], sP1[512], sSh[512], sHb2[256];
    int t = threadIdx.x, pb = blockIdx.x;
    int gn0 = pb * 32, b = pb >> 7;
    for (int i = t; i < 512; i += 256) {
        float s = sh1[i];
        sP0[i] = fmaf(s, hb1[i] + G1g[(b<<9)+i], th1[i]);
        sP1[i] = s * A1g[i];
        sSh[i] = s;
    }
    if (t < 256) sHb2[t] = hb2[t];
    {
        int s = t;
        int n = s >> 3, c16 = s & 7;
        int off = (c16*16) ^ ((n & 7) << 4);
        int sb8 = (t & 192) * 8;
        __builtin_amdgcn_global_load_lds((const char*)lfh + (size_t)(gn0+n)*128 + off, &sbh[sb8], 16, 0, 0);
        __builtin_amdgcn_global_load_lds((const char*)lfl + (size_t)(gn0+n)*128 + off, &sbl[sb8], 16, 0, 0);
    }
    __syncthreads();
    int lane = t & 63, wv = t >> 6, m = lane & 31, kg = lane >> 5;
    float mval = mb[gn0 + m];
    for (int ct = 0; ct < 4; ct++) {
        int ch0 = wv*128 + ct*32;
        f32x16 acc = {};
        #pragma unroll
        for (int ks = 0; ks < 4; ks++) {
            short8 ah = *(const short8*)(W1hi + (size_t)(ch0+m)*64 + ks*16 + kg*8);
            short8 al = *(const short8*)(W1lo + (size_t)(ch0+m)*64 + ks*16 + kg*8);
            int off = ((ks*16 + kg*8)*2) ^ ((m & 7) << 4);
            short8 bh = *(const short8*)((const char*)sbh + m*128 + off);
            short8 bl = *(const short8*)((const char*)sbl + m*128 + off);
            acc = mfma32(ah, bh, acc);
            acc = mfma32(ah, bl, acc);
            acc = mfma32(al, bh, acc);
        }
        #pragma unroll
        for (int q = 0; q < 4; q++) {
            ushort hs[4], ls[4];
            #pragma unroll
            for (int i = 0; i < 4; i++) {
                int r = q*4 + i;
                int chr = ch0 + i + 8*q + 4*kg;
                float a = fmaxf(fmaf(sSh[chr], acc[r], sP0[chr] + sP1[chr]*mval), 0.f);
                bsplit(a, hs[i], ls[i]);
            }
            int chb = ch0 + 8*q + 4*kg;
            int off = (chb*2) ^ ((m & 15) << 4);
            uint2 vh, vl;
            vh.x = (uint)hs[0] | ((uint)hs[1] << 16); vh.y = (uint)hs[2] | ((uint)hs[3] << 16);
            vl.x = (uint)ls[0] | ((uint)ls[1] << 16); vl.y = (uint)ls[2] | ((uint)ls[3] << 16);
            *(uint2*)((char*)a1h + m*1024 + off) = vh;
            *(uint2*)((char*)a1l + m*1024 + off) = vl;
        }
    }
    __syncthreads();
    f32x16 acc0 = {}, acc1 = {};
    for (int ks = 0; ks < 32; ks++) {
        int ko = ks*16 + kg*8;
        int off = (ko*2) ^ ((m & 15) << 4);
        short8 bh = *(const short8*)((const char*)a1h + m*1024 + off);
        short8 bl = *(const short8*)((const char*)a1l + m*1024 + off);
        short8 a0h = *(const short8*)(W2hi + (size_t)(wv*64+m)*512 + ko);
        short8 a0l = *(const short8*)(W2lo + (size_t)(wv*64+m)*512 + ko);
        short8 a1hh = *(const short8*)(W2hi + (size_t)(wv*64+32+m)*512 + ko);
        short8 a1ll = *(const short8*)(W2lo + (size_t)(wv*64+32+m)*512 + ko);
        acc0 = mfma32(a0h, bh, acc0);
        acc1 = mfma32(a1hh, bh, acc1);
        acc0 = mfma32(a0h, bl, acc0);
        acc1 = mfma32(a1hh, bl, acc1);
        acc0 = mfma32(a0l, bh, acc0);
        acc1 = mfma32(a1ll, bh, acc1);
    }
    #pragma unroll
    for (int ti = 0; ti < 2; ti++) {
        int ch0 = wv*64 + ti*32;
        #pragma unroll
        for (int r = 0; r < 16; r++) {
            int chr = ch0 + (r&3) + 8*(r>>2) + 4*kg;
            float v = (ti ? acc1[r] : acc0[r]) + sHb2[chr];
            pre2[(size_t)chr*65536 + gn0 + m] = v;
            float s = v, q = v*v;
            #pragma unroll
            for (int o = 16; o > 0; o >>= 1) { s += __shfl_xor(s, o); q += __shfl_xor(q, o); }
            if (m == 0) {
                parth2[(size_t)pb*512 + chr] = s;
                parth2[(size_t)pb*512 + 256 + chr] = q;
            }
        }
    }
}

// pre2 [256][65536] fp32 -> a2 hi/lo [n][256]
__global__ void k_a2t(const float* __restrict__ pre2, const float* __restrict__ sh2,
                      const float* __restrict__ th2, ushort* __restrict__ a2h,
                      ushort* __restrict__ a2l) {
    __shared__ float tile[32][33];
    int bi = blockIdx.x;
    int n0 = (bi & 2047) * 32, c0 = (bi >> 11) * 32;
    int t = threadIdx.x;
    int cr = t >> 3, j = (t & 7) * 4;
    float4 v = *(const float4*)(pre2 + (size_t)(c0+cr)*65536 + n0 + j);
    float s = sh2[c0+cr], tt = th2[c0+cr];
    tile[cr][j]   = fmaxf(fmaf(s, v.x, tt), 0.f);
    tile[cr][j+1] = fmaxf(fmaf(s, v.y, tt), 0.f);
    tile[cr][j+2] = fmaxf(fmaf(s, v.z, tt), 0.f);
    tile[cr][j+3] = fmaxf(fmaf(s, v.w, tt), 0.f);
    __syncthreads();
    int nr = t >> 3, cj = (t & 7) * 4;
    uint2 vh, vl;
    ushort hs[4], ls[4];
    #pragma unroll
    for (int i = 0; i < 4; i++) bsplit(tile[cj+i][nr], hs[i], ls[i]);
    vh.x = (uint)hs[0] | ((uint)hs[1] << 16); vh.y = (uint)hs[2] | ((uint)hs[3] << 16);
    vl.x = (uint)ls[0] | ((uint)ls[1] << 16); vl.y = (uint)ls[2] | ((uint)ls[3] << 16);
    *(uint2*)(a2h + (size_t)(n0+nr)*256 + c0 + cj) = vh;
    *(uint2*)(a2l + (size_t)(n0+nr)*256 + c0 + cj) = vl;
}

// h3 stats
__global__ __launch_bounds__(256, 2) void k_h3s(
    const ushort* __restrict__ a2h, const ushort* __restrict__ a2l,
    const ushort* __restrict__ W3hi, const ushort* __restrict__ W3lo,
    const float* __restrict__ hb3, float* __restrict__ parth3) {
    __shared__ ushort sbh[32*256], sbl[32*256];
    int t = threadIdx.x, pb = blockIdx.x;
    int lane = t & 63, wv = t >> 6, m = lane & 31, kg = lane >> 5;
    int ch0 = wv * 32;
    float bhr[16];
    #pragma unroll
    for (int r = 0; r < 16; r++) bhr[r] = hb3[ch0 + (r&3) + 8*(r>>2) + 4*kg];
    float ssum[16] = {}, ssq[16] = {};
    for (int pt = 0; pt < 4; pt++) {
        int gn0 = pb*128 + pt*32;
        __syncthreads();
        for (int it = 0; it < 4; it++) {
            int s = it*256 + t;
            int n = s >> 5, c16 = s & 31;
            int off = (c16*16) ^ ((n & 15) << 4);
            int sb8 = (it*256 + (t & 192)) * 8;
            __builtin_amdgcn_global_load_lds((const char*)a2h + (size_t)(gn0+n)*512 + off, &sbh[sb8], 16, 0, 0);
            __builtin_amdgcn_global_load_lds((const char*)a2l + (size_t)(gn0+n)*512 + off, &sbl[sb8], 16, 0, 0);
        }
        __syncthreads();
        f32x16 acc = {};
        for (int ks = 0; ks < 16; ks++) {
            int ko = ks*16 + kg*8;
            int off = (ko*2) ^ ((m & 15) << 4);
            short8 bh = *(const short8*)((const char*)sbh + m*512 + off);
            short8 bl = *(const short8*)((const char*)sbl + m*512 + off);
            short8 ah = *(const short8*)(W3hi + (size_t)(ch0+m)*256 + ko);
            short8 al = *(const short8*)(W3lo + (size_t)(ch0+m)*256 + ko);
            acc = mfma32(ah, bh, acc);
            acc = mfma32(ah, bl, acc);
            acc = mfma32(al, bh, acc);
        }
        #pragma unroll
        for (int r = 0; r < 16; r++) {
            float v = acc[r] + bhr[r];
            ssum[r] += v; ssq[r] = fmaf(v, v, ssq[r]);
        }
    }
    #pragma unroll
    for (int r = 0; r < 16; r++) {
        float s = ssum[r], q = ssq[r];
        #pragma unroll
        for (int o = 16; o > 0; o >>= 1) { s += __shfl_xor(s, o); q += __shfl_xor(q, o); }
        if (m == 0) {
            int chr = ch0 + (r&3) + 8*(r>>2) + 4*kg;
            parth3[(size_t)pb*256 + chr] = s;
            parth3[(size_t)pb*256 + 128 + chr] = q;
        }
    }
}

// h4
__global__ __launch_bounds__(256, 2) void k_h4m(
    const ushort* __restrict__ a2h, const ushort* __restrict__ a2l,
    const ushort* __restrict__ W3hi, const ushort* __restrict__ W3lo,
    const float* __restrict__ hb3, const float* __restrict__ sh3,
    const float* __restrict__ th3, const ushort* __restrict__ W4hi,
    const ushort* __restrict__ W4lo, const float* __restrict__ hb4,
    float* __restrict__ out) {
    __shared__ ushort sbh[32*256], sbl[32*256];
    __shared__ ushort a3h[32*128], a3l[32*128];
    __shared__ float sS[128], sT[128], sB[128];
    int t = threadIdx.x, pb = blockIdx.x;
    int gn0 = pb * 32;
    if (t < 128) { sS[t] = sh3[t]; sT[t] = th3[t]; sB[t] = hb3[t]; }
    for (int it = 0; it < 4; it++) {
        int s = it*256 + t;
        int n = s >> 5, c16 = s & 31;
        int off = (c16*16) ^ ((n & 15) << 4);
        int sb8 = (it*256 + (t & 192)) * 8;
        __builtin_amdgcn_global_load_lds((const char*)a2h + (size_t)(gn0+n)*512 + off, &sbh[sb8], 16, 0, 0);
        __builtin_amdgcn_global_load_lds((const char*)a2l + (size_t)(gn0+n)*512 + off, &sbl[sb8], 16, 0, 0);
    }
    __syncthreads();
    int lane = t & 63, wv = t >> 6, m = lane & 31, kg = lane >> 5;
    int ch0 = wv * 32;
    f32x16 acc = {};
    for (int ks = 0; ks < 16; ks++) {
        int ko = ks*16 + kg*8;
        int off = (ko*2) ^ ((m & 15) << 4);
        short8 bh = *(const short8*)((const char*)sbh + m*512 + off);
        short8 bl = *(const short8*)((const char*)sbl + m*512 + off);
        short8 ah = *(const short8*)(W3hi + (size_t)(ch0+m)*256 + ko);
        short8 al = *(const short8*)(W3lo + (size_t)(ch0+m)*256 + ko);
        acc = mfma32(ah, bh, acc);
        acc = mfma32(ah, bl, acc);
        acc = mfma32(al, bh, acc);
    }
    #pragma unroll
    for (int q = 0; q < 4; q++) {
        ushort hs[4], ls[4];
        #pragma unroll
        for (int i = 0; i < 4; i++) {
            int r = q*4 + i;
            int chr = ch0 + i + 8*q + 4*kg;
            float v = fmaxf(fmaf(sS[chr], acc[r] + sB[chr], sT[chr]), 0.f);
            bsplit(v, hs[i], ls[i]);
        }
        int chb = ch0 + 8*q + 4*kg;
        int off = (chb*2) ^ ((m & 15) << 4);
        uint2 vh, vl;
        vh.x = (uint)hs[0] | ((uint)hs[1] << 16); vh.y = (uint)hs[2] | ((uint)hs[3] << 16);
        vl.x = (uint)ls[0] | ((uint)ls[1] << 16); vl.y = (uint)ls[2] | ((uint)ls[3] << 16);
        *(uint2*)((char*)a3h + m*256 + off) = vh;
        *(uint2*)((char*)a3l + m*256 + off) = vl;
    }
    __syncthreads();
    if (wv == 0) {
        f32x16 acc2 = {};
        for (int ks = 0; ks < 8; ks++) {
            int ko = ks*16 + kg*8;
            int off = (ko*2) ^ ((m & 15) << 4);
            short8 bh = *(const short8*)((const char*)a3h + m*256 + off);
            short8 bl = *(const short8*)((const char*)a3l + m*256 + off);
            short8 ah = *(const short8*)(W4hi + (size_t)m*128 + ko);
            short8 al = *(const short8*)(W4lo + (size_t)m*128 + ko);
            acc2 = mfma32(ah, bh, acc2);
            acc2 = mfma32(ah, bl, acc2);
            acc2 = mfma32(al, bh, acc2);
        }
        #pragma unroll
        for (int r = 0; r < 16; r++) {
            int mrow = (r&3) + 8*(r>>2) + 4*kg;
            if (mrow < 6) out[(size_t)(gn0+m)*6 + mrow] = acc2[r] + hb4[mrow];
        }
    }
}

extern "C" void kernel_launch(void* const* d_in, const int* in_sizes, int n_in,
                              void* d_out, int out_size, void* d_ws, size_t ws_size,
                              hipStream_t stream) {
    const float* pts  = (const float*)d_in[0];
    const float* w1   = (const float*)d_in[1];
    const float* b1   = (const float*)d_in[2];
    const float* g1   = (const float*)d_in[3];
    const float* be1  = (const float*)d_in[4];
    const float* w3   = (const float*)d_in[5];
    const float* b3   = (const float*)d_in[6];
    const float* g3   = (const float*)d_in[7];
    const float* be3  = (const float*)d_in[8];
    const float* hw1  = (const float*)d_in[9];
    const float* hb1  = (const float*)d_in[10];
    const float* hg1  = (const float*)d_in[11];
    const float* hbe1 = (const float*)d_in[12];
    const float* hw2  = (const float*)d_in[13];
    const float* hb2  = (const float*)d_in[14];
    const float* hg2  = (const float*)d_in[15];
    const float* hbe2 = (const float*)d_in[16];
    const float* hw3  = (const float*)d_in[17];
    const float* hb3  = (const float*)d_in[18];
    const float* hg3  = (const float*)d_in[19];
    const float* hbe3 = (const float*)d_in[20];
    const float* hw4  = (const float*)d_in[21];
    const float* hb4  = (const float*)d_in[22];
    (void)in_sizes; (void)n_in; (void)out_size; (void)ws_size;

    float* W = (float*)d_ws;
    size_t off = 0;
    auto alloc = [&](size_t n) { float* p = W + off; off += n; return p; };
    auto allocU = [&](size_t nshorts) { return (ushort*)alloc((nshorts + 1) / 2); };

    ushort* lfh  = allocU(65536UL*64);
    ushort* lfl  = allocU(65536UL*64);
    ushort* a2h  = allocU(65536UL*256);
    ushort* a2l  = allocU(65536UL*256);
    ushort* w3h  = allocU(512*64);  ushort* w3l  = allocU(512*64);
    ushort* w1eh = allocU(512*64);  ushort* w1el = allocU(512*64);
    ushort* w2h  = allocU(256*512); ushort* w2l  = allocU(256*512);
    ushort* wh3h = allocU(128*256); ushort* wh3l = allocU(128*256);
    ushort* w4h  = allocU(32*128);  ushort* w4l  = allocU(32*128);
    float* y38    = alloc(524288);
    float* mbuf   = alloc(65536);
    float* gmaxb  = alloc(8192);
    float* G1     = alloc(8192);
    float* A1     = alloc(512);
    float* s1 = alloc(64);  float* t1 = alloc(64);
    float* s3 = alloc(512); float* t3 = alloc(512);
    float* sh1 = alloc(512); float* th1 = alloc(512);
    float* sh2 = alloc(256); float* th2 = alloc(256);
    float* sh3 = alloc(128); float* th3 = alloc(128);
    float* part1  = alloc(32768);
    float* part3  = alloc(512*1536);
    float* parth1 = alloc(512*1024);
    float* parth2 = alloc(2048*512);
    float* parth3 = alloc(512*256);
    float* pre2   = alloc(16777216);

    k_wsplit<<<128, 256, 0, stream>>>(w3, 64, 0, 512, 64, w3h, w3l, 512);
    k_wsplit<<<128, 256, 0, stream>>>(hw1, 1088, 512, 512, 64, w1eh, w1el, 512);
    k_wsplit<<<512, 256, 0, stream>>>(hw2, 512, 0, 256, 512, w2h, w2l, 256);
    k_wsplit<<<128, 256, 0, stream>>>(hw3, 256, 0, 128, 256, wh3h, wh3l, 128);
    k_wsplit<<<16, 256, 0, stream>>>(hw4, 128, 0, 6, 128, w4h, w4l, 32);

    k_stats1<<<256, 256, 0, stream>>>(pts, w1, b1, part1);
    k_fin<<<64, 256, 0, stream>>>(part1, 256, 128, 64, g1, be1, s1, t1);
    k_lfeat2<<<256, 256, 0, stream>>>(pts, w1, b1, s1, t1, lfh, lfl);
    k_gemm64<0><<<512, 256, 0, stream>>>(lfh, lfl, w3h, w3l, b3, nullptr, nullptr, nullptr, part3, y38);
    k_fin<<<512, 256, 0, stream>>>(part3, 512, 1536, 512, g3, be3, s3, t3);
    k_fin3b<<<16, 512, 0, stream>>>(part3, s3, t3, gmaxb);
    k_a1g1<<<17, 256, 0, stream>>>(hw1, gmaxb, A1, G1);
    k_knn<<<2048, 256, 0, stream>>>(pts, y38, s3, t3, mbuf);
    k_gemm64<1><<<512, 256, 0, stream>>>(lfh, lfl, w1eh, w1el, hb1, A1, G1, mbuf, parth1, nullptr);
    k_fin<<<512, 256, 0, stream>>>(parth1, 512, 1024, 512, hg1, hbe1, sh1, th1);
    k_h2m<<<2048, 256, 0, stream>>>(lfh, lfl, w1eh, w1el, w2h, w2l, hb1, A1, G1, mbuf,
                                    sh1, th1, hb2, pre2, parth2);
    k_fin<<<256, 256, 0, stream>>>(parth2, 2048, 512, 256, hg2, hbe2, sh2, th2);
    k_a2t<<<16384, 256, 0, stream>>>(pre2, sh2, th2, a2h, a2l);
    k_h3s<<<512, 256, 0, stream>>>(a2h, a2l, wh3h, wh3l, hb3, parth3);
    k_fin<<<128, 256, 0, stream>>>(parth3, 512, 256, 128, hg3, hbe3, sh3, th3);
    k_h4m<<<2048, 256, 0, stream>>>(a2h, a2l, wh3h, wh3l, hb3, sh3, th3, w4h, w4l, hb4, (float*)d_out);
}

// Round 5
// 737.205 us; speedup vs baseline: 5.6730x; 1.1541x over previous
//
#include <hip/hip_runtime.h>
#include <hip/hip_bf16.h>
#include <math.h>

typedef __attribute__((ext_vector_type(8))) short short8;
typedef __attribute__((ext_vector_type(16))) float f32x16;

__device__ inline f32x16 mfma32(short8 a, short8 b, f32x16 c) {
    return __builtin_amdgcn_mfma_f32_32x32x16_bf16(a, b, c, 0, 0, 0);
}

__device__ inline void bsplit(float x, ushort& h, ushort& l) {
    __hip_bfloat16 bh = __float2bfloat16(x);
    float hf = __bfloat162float(bh);
    __hip_bfloat16 bl = __float2bfloat16(x - hf);
    h = *reinterpret_cast<ushort*>(&bh);
    l = *reinterpret_cast<ushort*>(&bl);
}

// ---------------------------------------------------------------------------
// Weight convert: W[o][k] (strided src) -> hi/lo ushort planes [Mdst][K]
__global__ void k_wsplit(const float* __restrict__ src, int rowStride, int colOff,
                         int Msrc, int K, ushort* __restrict__ hi,
                         ushort* __restrict__ lo, int Mdst) {
    int i = blockIdx.x * 256 + threadIdx.x;
    if (i >= Mdst * K) return;
    int o = i / K, k = i - o * K;
    float x = (o < Msrc) ? src[(size_t)o * rowStride + colOff + k] : 0.f;
    ushort h, l;
    bsplit(x, h, l);
    hi[i] = h; lo[i] = l;
}

// ---------------------------------------------------------------------------
// Layer 1 stats
__global__ void k_stats1(const float* __restrict__ pts, const float* __restrict__ w1,
                         const float* __restrict__ b1, float* __restrict__ part1) {
    __shared__ float sw[256];
    __shared__ float wred[2][4][64];
    int t = threadIdx.x;
    if (t < 192) sw[t] = w1[t];
    if (t < 64) sw[192 + t] = b1[t];
    __syncthreads();
    int g = blockIdx.x * 256 + t;
    float p0 = pts[g*3], p1 = pts[g*3+1], p2 = pts[g*3+2];
    int lane = t & 63, wv = t >> 6;
    for (int c = 0; c < 64; c++) {
        float y = fmaf(sw[c*3+2], p2, fmaf(sw[c*3+1], p1, fmaf(sw[c*3], p0, sw[192+c])));
        float s = y, q = y * y;
        #pragma unroll
        for (int o = 32; o > 0; o >>= 1) { s += __shfl_down(s, o); q += __shfl_down(q, o); }
        if (lane == 0) { wred[0][wv][c] = s; wred[1][wv][c] = q; }
    }
    __syncthreads();
    if (t < 64) {
        float s = wred[0][0][t] + wred[0][1][t] + wred[0][2][t] + wred[0][3][t];
        float q = wred[1][0][t] + wred[1][1][t] + wred[1][2][t] + wred[1][3][t];
        part1[blockIdx.x * 128 + t] = s;
        part1[blockIdx.x * 128 + 64 + t] = q;
    }
}

// Generic BN-stat finalize
__global__ void k_fin(const float* __restrict__ part, int count, int stride, int sqoff,
                      const float* __restrict__ g, const float* __restrict__ be,
                      float* __restrict__ sout, float* __restrict__ tout) {
    int c = blockIdx.x, t = threadIdx.x;
    float s = 0.f, q = 0.f;
    for (int w = t; w < count; w += 256) { s += part[(size_t)w*stride + c]; q += part[(size_t)w*stride + sqoff + c]; }
    __shared__ float rs[4], rq[4];
    int lane = t & 63, wv = t >> 6;
    #pragma unroll
    for (int o = 32; o > 0; o >>= 1) { s += __shfl_down(s, o); q += __shfl_down(q, o); }
    if (lane == 0) { rs[wv] = s; rq[wv] = q; }
    __syncthreads();
    if (t == 0) {
        s = rs[0] + rs[1] + rs[2] + rs[3];
        q = rq[0] + rq[1] + rq[2] + rq[3];
        float mean = s / 65536.f;
        float var = q / 65536.f - mean * mean;
        float sc = g[c] * rsqrtf(var + 1e-5f);
        sout[c] = sc;
        tout[c] = be[c] - mean * sc;
    }
}

// l_feat bf16 hi/lo planes, layout [n][64]
__global__ void k_lfeat2(const float* __restrict__ pts, const float* __restrict__ w1,
                         const float* __restrict__ b1, const float* __restrict__ s1,
                         const float* __restrict__ t1, ushort* __restrict__ lfh,
                         ushort* __restrict__ lfl) {
    __shared__ float sw[256], ss[64], st[64];
    int t = threadIdx.x;
    if (t < 192) sw[t] = w1[t];
    if (t < 64) { sw[192+t] = b1[t]; ss[t] = s1[t]; st[t] = t1[t]; }
    __syncthreads();
    int g = blockIdx.x * 256 + t;
    float p0 = pts[g*3], p1 = pts[g*3+1], p2 = pts[g*3+2];
    for (int c0 = 0; c0 < 64; c0 += 8) {
        union { short8 v; ushort u[8]; } H, L;
        #pragma unroll
        for (int j = 0; j < 8; j++) {
            int c = c0 + j;
            float y = fmaf(sw[c*3+2], p2, fmaf(sw[c*3+1], p1, fmaf(sw[c*3], p0, sw[192+c])));
            float a = fmaxf(fmaf(ss[c], y, st[c]), 0.f);
            bsplit(a, H.u[j], L.u[j]);
        }
        *(short8*)(lfh + (size_t)g*64 + c0) = H.v;
        *(short8*)(lfl + (size_t)g*64 + c0) = L.v;
    }
}

// ---------------------------------------------------------------------------
// K=64 MFMA GEMM: MODE 0 = conv3 (stats s/q/max + y38), MODE 1 = h1 stats
template<int MODE>
__global__ __launch_bounds__(256, 2) void k_gemm64(
    const ushort* __restrict__ Bhi, const ushort* __restrict__ Blo,
    const ushort* __restrict__ Ahi, const ushort* __restrict__ Alo,
    const float* __restrict__ bias, const float* __restrict__ A1,
    const float* __restrict__ G1, const float* __restrict__ mb,
    float* __restrict__ part, float* __restrict__ y38) {
    __shared__ ushort sbh[128*64], sbl[128*64];
    __shared__ float sPb[512], sPa[512];
    int t = threadIdx.x, pb = blockIdx.x;
    int gn0 = pb * 128, b = pb >> 5;
    for (int i = t; i < 512; i += 256) {
        float bb = bias[i];
        if (MODE) bb += G1[(b<<9) + i];
        sPb[i] = bb;
        sPa[i] = MODE ? A1[i] : 0.f;
    }
    for (int it = 0; it < 4; it++) {
        int s = it*256 + t;
        int n = s >> 3, c16 = s & 7;
        int off = (c16*16) ^ ((n & 7) << 4);
        int sb8 = (it*256 + (t & 192)) * 8;
        __builtin_amdgcn_global_load_lds((const char*)Bhi + (size_t)(gn0+n)*128 + off, &sbh[sb8], 16, 0, 0);
        __builtin_amdgcn_global_load_lds((const char*)Blo + (size_t)(gn0+n)*128 + off, &sbl[sb8], 16, 0, 0);
    }
    __syncthreads();
    int lane = t & 63, wv = t >> 6, m = lane & 31, kg = lane >> 5;
    for (int ct = 0; ct < 4; ct++) {
        int ch0 = wv*128 + ct*32;
        short8 ah[4], al[4];
        #pragma unroll
        for (int ks = 0; ks < 4; ks++) {
            ah[ks] = *(const short8*)(Ahi + (size_t)(ch0+m)*64 + ks*16 + kg*8);
            al[ks] = *(const short8*)(Alo + (size_t)(ch0+m)*64 + ks*16 + kg*8);
        }
        float ssum[16] = {}, ssq[16] = {}, smx[16];
        #pragma unroll
        for (int r = 0; r < 16; r++) smx[r] = -__builtin_inff();
        for (int pt = 0; pt < 4; pt++) {
            int n = pt*32 + m;
            f32x16 acc = {};
            #pragma unroll
            for (int ks = 0; ks < 4; ks++) {
                int off = ((ks*16 + kg*8)*2) ^ ((n & 7) << 4);
                short8 bh = *(const short8*)((const char*)sbh + n*128 + off);
                short8 bl = *(const short8*)((const char*)sbl + n*128 + off);
                acc = mfma32(ah[ks], bh, acc);
                acc = mfma32(ah[ks], bl, acc);
                acc = mfma32(al[ks], bh, acc);
            }
            float mval = MODE ? mb[gn0 + n] : 0.f;
            #pragma unroll
            for (int r = 0; r < 16; r++) {
                int chr = ch0 + (r&3) + 8*(r>>2) + 4*kg;
                float v = acc[r] + sPb[chr] + (MODE ? sPa[chr]*mval : 0.f);
                ssum[r] += v; ssq[r] = fmaf(v, v, ssq[r]);
                if (MODE == 0) {
                    smx[r] = fmaxf(smx[r], v);
                    if (wv == 0 && ct == 0 && r < 4) {
                        int c8 = (r&3) + 4*kg;  // 0..7
                        y38[(size_t)c8*65536 + gn0 + n] = v;
                    }
                }
            }
        }
        #pragma unroll
        for (int r = 0; r < 16; r++) {
            float s = ssum[r], q = ssq[r], x = smx[r];
            #pragma unroll
            for (int o = 16; o > 0; o >>= 1) {
                s += __shfl_xor(s, o); q += __shfl_xor(q, o);
                if (MODE == 0) x = fmaxf(x, __shfl_xor(x, o));
            }
            if (m == 0) {
                int chr = ch0 + (r&3) + 8*(r>>2) + 4*kg;
                if (MODE == 0) {
                    part[(size_t)pb*1536 + chr] = s;
                    part[(size_t)pb*1536 + 512 + chr] = q;
                    part[(size_t)pb*1536 + 1024 + chr] = x;
                } else {
                    part[(size_t)pb*1024 + chr] = s;
                    part[(size_t)pb*1024 + 512 + chr] = q;
                }
            }
        }
    }
}

// gmax[b,c] = relu(s3*max + t3); part3 blocks 32 per batch
__global__ void k_fin3b(const float* __restrict__ part3, const float* __restrict__ s3,
                        const float* __restrict__ t3, float* __restrict__ gmaxb) {
    int b = blockIdx.x, c = threadIdx.x;
    float mx = -__builtin_inff();
    for (int i = 0; i < 32; i++) mx = fmaxf(mx, part3[(size_t)(b*32+i)*1536 + 1024 + c]);
    gmaxb[(b<<9)+c] = fmaxf(fmaf(s3[c], mx, t3[c]), 0.f);
}

__global__ void k_a1g1(const float* __restrict__ hw1, const float* __restrict__ gmaxb,
                       float* __restrict__ A1, float* __restrict__ G1) {
    int blk = blockIdx.x, t = threadIdx.x;
    if (blk == 16) {
        for (int o = t; o < 512; o += 256) {
            float s = 0.f;
            for (int c = 0; c < 512; c++) s += hw1[o*1088 + c];
            A1[o] = s;
        }
    } else {
        int b = blk;
        for (int o = t; o < 512; o += 256) {
            float s = 0.f;
            for (int c = 0; c < 512; c++) s = fmaf(hw1[o*1088 + 576 + c], gmaxb[(b<<9)+c], s);
            G1[(b<<9)+o] = s;
        }
    }
}

// ---------------------------------------------------------------------------
// KNN v4: float32 keys + idx payload, group-shared prune threshold,
// wave-uniform skip branch. Exact fp32 dist arithmetic identical to reference.
// Correctness notes:
//  - d can never be -0.0 (a>=0, fsub(a,b)=0 has +0 sign) or NaN, so strict
//    float < equals the monotone-mapped u32/u64 order used for final merge.
//  - within a lane, incoming idx > all stored idx, so strict < (ties lose)
//    implements lexicographic (d, idx) exactly; cross-lane ties resolved by
//    the u64 bitonic merge at the end.
//  - prune thr = min over the query's 8 lanes of local kd[7]; every lane has
//    <= 7 elements < group-8th, so local kd[7] >= group-8th >= final-8th;
//    pruning d > thr (strict) is therefore exact (equal-d candidates pass).
__global__ __launch_bounds__(256, 8)
void k_knn(const float* __restrict__ pts, const float* __restrict__ y38,
           const float* __restrict__ s3, const float* __restrict__ t3,
           float* __restrict__ mbuf) {
    __shared__ float4 sp[512];
    int t = threadIdx.x, blk = blockIdx.x;
    int b = blk >> 7;
    int n = (blk & 127) * 32 + (t >> 3);
    int c = t & 7;
    const float* pb = pts + (size_t)b * 4096 * 3;
    float q0 = pb[n*3], q1 = pb[n*3+1], q2 = pb[n*3+2];
    float qx2 = __fadd_rn(__fadd_rn(__fmul_rn(q0,q0), __fmul_rn(q1,q1)), __fmul_rn(q2,q2));
    float kdf[8]; unsigned int kif[8];
    #pragma unroll
    for (int k = 0; k < 8; k++) { kdf[k] = __builtin_inff(); kif[k] = 0x7fffffffu; }
    float thr = __builtin_inff();
    for (int w = 0; w < 8; w++) {
        __syncthreads();
        for (int i = t; i < 512; i += 256) {
            int m = w*512 + i;
            float c0 = pb[m*3], c1 = pb[m*3+1], c2 = pb[m*3+2];
            float cw = __fadd_rn(__fadd_rn(__fmul_rn(c0,c0), __fmul_rn(c1,c1)), __fmul_rn(c2,c2));
            sp[i] = make_float4(c0, c1, c2, cw);
        }
        __syncthreads();
        for (int j = 0; j < 64; j++) {
            float4 cp = sp[j*8 + c];
            float dot = __fadd_rn(__fadd_rn(__fmul_rn(q0,cp.x), __fmul_rn(q1,cp.y)), __fmul_rn(q2,cp.z));
            float d = __fsub_rn(__fadd_rn(qx2, cp.w), __fmul_rn(2.f, dot));
            bool p = (d <= thr);
            if (__ballot(p) != 0ull) {
                unsigned int m = (unsigned int)(w*512 + j*8 + c);
                bool hit = p && (d < kdf[7]);
                kdf[7] = hit ? d : kdf[7];
                kif[7] = hit ? m : kif[7];
                #pragma unroll
                for (int j2 = 7; j2 > 0; j2--) {
                    bool sw = kdf[j2] < kdf[j2-1];
                    float da = kdf[j2-1], db = kdf[j2];
                    kdf[j2-1] = sw ? db : da; kdf[j2] = sw ? da : db;
                    unsigned int ia = kif[j2-1], ib = kif[j2];
                    kif[j2-1] = sw ? ib : ia; kif[j2] = sw ? ia : ib;
                }
            }
            if ((j & 7) == 7) {
                float g = kdf[7];
                g = fminf(g, __shfl_xor(g, 1));
                g = fminf(g, __shfl_xor(g, 2));
                g = fminf(g, __shfl_xor(g, 4));
                thr = g;
            }
        }
    }
    // build sortable u64 keys and merge 8 sorted lists across the 8 lanes
    unsigned long long kd[8];
    #pragma unroll
    for (int k = 0; k < 8; k++) {
        unsigned int db = __float_as_uint(kdf[k]);
        unsigned int mp = db ^ (0x80000000u | (unsigned int)((int)db >> 31));
        kd[k] = ((unsigned long long)mp << 32) | kif[k];
    }
    #pragma unroll
    for (int st = 1; st <= 4; st <<= 1) {
        unsigned long long nd[8];
        #pragma unroll
        for (int k = 0; k < 8; k++) {
            unsigned long long pd = __shfl_xor(kd[7-k], st);
            nd[k] = (pd < kd[k]) ? pd : kd[k];
        }
        #define CASM(k1,k2) { unsigned long long a_ = nd[k1], b_ = nd[k2]; \
            bool sw_ = b_ < a_; nd[k1] = sw_ ? b_ : a_; nd[k2] = sw_ ? a_ : b_; }
        CASM(0,4) CASM(1,5) CASM(2,6) CASM(3,7)
        CASM(0,2) CASM(1,3) CASM(4,6) CASM(5,7)
        CASM(0,1) CASM(2,3) CASM(4,5) CASM(6,7)
        #undef CASM
        #pragma unroll
        for (int k = 0; k < 8; k++) kd[k] = nd[k];
    }
    // m[b,n] = max_k relu(s3[k]*y3[k, idx_k] + t3[k]); lane c handles k = c
    unsigned int idx = (unsigned int)(kd[c] & 0xffffffffull);
    float y = y38[(size_t)c*65536 + (b<<12) + (idx & 4095)];
    float mv = fmaxf(fmaf(s3[c], y, t3[c]), 0.f);
    #pragma unroll
    for (int st = 1; st <= 4; st <<= 1) mv = fmaxf(mv, __shfl_xor(mv, st));
    if (c == 0) mbuf[(b<<12)+n] = mv;
}

// ---------------------------------------------------------------------------
// h2: phase1 recompute a1 (512ch) -> LDS bf16 hi/lo; phase2 pre2 = hw2 @ a1.
__global__ __launch_bounds__(256, 2) void k_h2m(
    const ushort* __restrict__ lfh, const ushort* __restrict__ lfl,
    const ushort* __restrict__ W1hi, const ushort* __restrict__ W1lo,
    const ushort* __restrict__ W2hi, const ushort* __restrict__ W2lo,
    const float* __restrict__ hb1, const float* __restrict__ A1g,
    const float* __restrict__ G1g, const float* __restrict__ mb,
    const float* __restrict__ sh1, const float* __restrict__ th1,
    const float* __restrict__ hb2,
    float* __restrict__ pre2, float* __restrict__ parth2) {
    __shared__ ushort sbh[32*64], sbl[32*64];    // 4+4 KB
    __shared__ ushort a1h[32*512], a1l[32*512];  // 32+32 KB
    __shared__ float sP0[512], sP1[512], sSh[512], sHb2[256];
    int t = threadIdx.x, pb = blockIdx.x;
    int gn0 = pb * 32, b = pb >> 7;
    for (int i = t; i < 512; i += 256) {
        float s = sh1[i];
        sP0[i] = fmaf(s, hb1[i] + G1g[(b<<9)+i], th1[i]);
        sP1[i] = s * A1g[i];
        sSh[i] = s;
    }
    if (t < 256) sHb2[t] = hb2[t];
    {
        int s = t;
        int n = s >> 3, c16 = s & 7;
        int off = (c16*16) ^ ((n & 7) << 4);
        int sb8 = (t & 192) * 8;
        __builtin_amdgcn_global_load_lds((const char*)lfh + (size_t)(gn0+n)*128 + off, &sbh[sb8], 16, 0, 0);
        __builtin_amdgcn_global_load_lds((const char*)lfl + (size_t)(gn0+n)*128 + off, &sbl[sb8], 16, 0, 0);
    }
    __syncthreads();
    int lane = t & 63, wv = t >> 6, m = lane & 31, kg = lane >> 5;
    float mval = mb[gn0 + m];
    for (int ct = 0; ct < 4; ct++) {
        int ch0 = wv*128 + ct*32;
        f32x16 acc = {};
        #pragma unroll
        for (int ks = 0; ks < 4; ks++) {
            short8 ah = *(const short8*)(W1hi + (size_t)(ch0+m)*64 + ks*16 + kg*8);
            short8 al = *(const short8*)(W1lo + (size_t)(ch0+m)*64 + ks*16 + kg*8);
            int off = ((ks*16 + kg*8)*2) ^ ((m & 7) << 4);
            short8 bh = *(const short8*)((const char*)sbh + m*128 + off);
            short8 bl = *(const short8*)((const char*)sbl + m*128 + off);
            acc = mfma32(ah, bh, acc);
            acc = mfma32(ah, bl, acc);
            acc = mfma32(al, bh, acc);
        }
        #pragma unroll
        for (int q = 0; q < 4; q++) {
            ushort hs[4], ls[4];
            #pragma unroll
            for (int i = 0; i < 4; i++) {
                int r = q*4 + i;
                int chr = ch0 + i + 8*q + 4*kg;
                float a = fmaxf(fmaf(sSh[chr], acc[r], sP0[chr] + sP1[chr]*mval), 0.f);
                bsplit(a, hs[i], ls[i]);
            }
            int chb = ch0 + 8*q + 4*kg;
            int off = (chb*2) ^ ((m & 15) << 4);
            uint2 vh, vl;
            vh.x = (uint)hs[0] | ((uint)hs[1] << 16); vh.y = (uint)hs[2] | ((uint)hs[3] << 16);
            vl.x = (uint)ls[0] | ((uint)ls[1] << 16); vl.y = (uint)ls[2] | ((uint)ls[3] << 16);
            *(uint2*)((char*)a1h + m*1024 + off) = vh;
            *(uint2*)((char*)a1l + m*1024 + off) = vl;
        }
    }
    __syncthreads();
    f32x16 acc0 = {}, acc1 = {};
    for (int ks = 0; ks < 32; ks++) {
        int ko = ks*16 + kg*8;
        int off = (ko*2) ^ ((m & 15) << 4);
        short8 bh = *(const short8*)((const char*)a1h + m*1024 + off);
        short8 bl = *(const short8*)((const char*)a1l + m*1024 + off);
        short8 a0h = *(const short8*)(W2hi + (size_t)(wv*64+m)*512 + ko);
        short8 a0l = *(const short8*)(W2lo + (size_t)(wv*64+m)*512 + ko);
        short8 a1hh = *(const short8*)(W2hi + (size_t)(wv*64+32+m)*512 + ko);
        short8 a1ll = *(const short8*)(W2lo + (size_t)(wv*64+32+m)*512 + ko);
        acc0 = mfma32(a0h, bh, acc0);
        acc1 = mfma32(a1hh, bh, acc1);
        acc0 = mfma32(a0h, bl, acc0);
        acc1 = mfma32(a1hh, bl, acc1);
        acc0 = mfma32(a0l, bh, acc0);
        acc1 = mfma32(a1ll, bh, acc1);
    }
    #pragma unroll
    for (int ti = 0; ti < 2; ti++) {
        int ch0 = wv*64 + ti*32;
        #pragma unroll
        for (int r = 0; r < 16; r++) {
            int chr = ch0 + (r&3) + 8*(r>>2) + 4*kg;
            float v = (ti ? acc1[r] : acc0[r]) + sHb2[chr];
            pre2[(size_t)chr*65536 + gn0 + m] = v;
            float s = v, q = v*v;
            #pragma unroll
            for (int o = 16; o > 0; o >>= 1) { s += __shfl_xor(s, o); q += __shfl_xor(q, o); }
            if (m == 0) {
                parth2[(size_t)pb*512 + chr] = s;
                parth2[(size_t)pb*512 + 256 + chr] = q;
            }
        }
    }
}

// pre2 [256][65536] fp32 -> a2 hi/lo [n][256]
__global__ void k_a2t(const float* __restrict__ pre2, const float* __restrict__ sh2,
                      const float* __restrict__ th2, ushort* __restrict__ a2h,
                      ushort* __restrict__ a2l) {
    __shared__ float tile[32][33];
    int bi = blockIdx.x;
    int n0 = (bi & 2047) * 32, c0 = (bi >> 11) * 32;
    int t = threadIdx.x;
    int cr = t >> 3, j = (t & 7) * 4;
    float4 v = *(const float4*)(pre2 + (size_t)(c0+cr)*65536 + n0 + j);
    float s = sh2[c0+cr], tt = th2[c0+cr];
    tile[cr][j]   = fmaxf(fmaf(s, v.x, tt), 0.f);
    tile[cr][j+1] = fmaxf(fmaf(s, v.y, tt), 0.f);
    tile[cr][j+2] = fmaxf(fmaf(s, v.z, tt), 0.f);
    tile[cr][j+3] = fmaxf(fmaf(s, v.w, tt), 0.f);
    __syncthreads();
    int nr = t >> 3, cj = (t & 7) * 4;
    uint2 vh, vl;
    ushort hs[4], ls[4];
    #pragma unroll
    for (int i = 0; i < 4; i++) bsplit(tile[cj+i][nr], hs[i], ls[i]);
    vh.x = (uint)hs[0] | ((uint)hs[1] << 16); vh.y = (uint)hs[2] | ((uint)hs[3] << 16);
    vl.x = (uint)ls[0] | ((uint)ls[1] << 16); vl.y = (uint)ls[2] | ((uint)ls[3] << 16);
    *(uint2*)(a2h + (size_t)(n0+nr)*256 + c0 + cj) = vh;
    *(uint2*)(a2l + (size_t)(n0+nr)*256 + c0 + cj) = vl;
}

// h3 stats
__global__ __launch_bounds__(256, 2) void k_h3s(
    const ushort* __restrict__ a2h, const ushort* __restrict__ a2l,
    const ushort* __restrict__ W3hi, const ushort* __restrict__ W3lo,
    const float* __restrict__ hb3, float* __restrict__ parth3) {
    __shared__ ushort sbh[32*256], sbl[32*256];
    int t = threadIdx.x, pb = blockIdx.x;
    int lane = t & 63, wv = t >> 6, m = lane & 31, kg = lane >> 5;
    int ch0 = wv * 32;
    float bhr[16];
    #pragma unroll
    for (int r = 0; r < 16; r++) bhr[r] = hb3[ch0 + (r&3) + 8*(r>>2) + 4*kg];
    float ssum[16] = {}, ssq[16] = {};
    for (int pt = 0; pt < 4; pt++) {
        int gn0 = pb*128 + pt*32;
        __syncthreads();
        for (int it = 0; it < 4; it++) {
            int s = it*256 + t;
            int n = s >> 5, c16 = s & 31;
            int off = (c16*16) ^ ((n & 15) << 4);
            int sb8 = (it*256 + (t & 192)) * 8;
            __builtin_amdgcn_global_load_lds((const char*)a2h + (size_t)(gn0+n)*512 + off, &sbh[sb8], 16, 0, 0);
            __builtin_amdgcn_global_load_lds((const char*)a2l + (size_t)(gn0+n)*512 + off, &sbl[sb8], 16, 0, 0);
        }
        __syncthreads();
        f32x16 acc = {};
        for (int ks = 0; ks < 16; ks++) {
            int ko = ks*16 + kg*8;
            int off = (ko*2) ^ ((m & 15) << 4);
            short8 bh = *(const short8*)((const char*)sbh + m*512 + off);
            short8 bl = *(const short8*)((const char*)sbl + m*512 + off);
            short8 ah = *(const short8*)(W3hi + (size_t)(ch0+m)*256 + ko);
            short8 al = *(const short8*)(W3lo + (size_t)(ch0+m)*256 + ko);
            acc = mfma32(ah, bh, acc);
            acc = mfma32(ah, bl, acc);
            acc = mfma32(al, bh, acc);
        }
        #pragma unroll
        for (int r = 0; r < 16; r++) {
            float v = acc[r] + bhr[r];
            ssum[r] += v; ssq[r] = fmaf(v, v, ssq[r]);
        }
    }
    #pragma unroll
    for (int r = 0; r < 16; r++) {
        float s = ssum[r], q = ssq[r];
        #pragma unroll
        for (int o = 16; o > 0; o >>= 1) { s += __shfl_xor(s, o); q += __shfl_xor(q, o); }
        if (m == 0) {
            int chr = ch0 + (r&3) + 8*(r>>2) + 4*kg;
            parth3[(size_t)pb*256 + chr] = s;
            parth3[(size_t)pb*256 + 128 + chr] = q;
        }
    }
}

// h4
__global__ __launch_bounds__(256, 2) void k_h4m(
    const ushort* __restrict__ a2h, const ushort* __restrict__ a2l,
    const ushort* __restrict__ W3hi, const ushort* __restrict__ W3lo,
    const float* __restrict__ hb3, const float* __restrict__ sh3,
    const float* __restrict__ th3, const ushort* __restrict__ W4hi,
    const ushort* __restrict__ W4lo, const float* __restrict__ hb4,
    float* __restrict__ out) {
    __shared__ ushort sbh[32*256], sbl[32*256];
    __shared__ ushort a3h[32*128], a3l[32*128];
    __shared__ float sS[128], sT[128], sB[128];
    int t = threadIdx.x, pb = blockIdx.x;
    int gn0 = pb * 32;
    if (t < 128) { sS[t] = sh3[t]; sT[t] = th3[t]; sB[t] = hb3[t]; }
    for (int it = 0; it < 4; it++) {
        int s = it*256 + t;
        int n = s >> 5, c16 = s & 31;
        int off = (c16*16) ^ ((n & 15) << 4);
        int sb8 = (it*256 + (t & 192)) * 8;
        __builtin_amdgcn_global_load_lds((const char*)a2h + (size_t)(gn0+n)*512 + off, &sbh[sb8], 16, 0, 0);
        __builtin_amdgcn_global_load_lds((const char*)a2l + (size_t)(gn0+n)*512 + off, &sbl[sb8], 16, 0, 0);
    }
    __syncthreads();
    int lane = t & 63, wv = t >> 6, m = lane & 31, kg = lane >> 5;
    int ch0 = wv * 32;
    f32x16 acc = {};
    for (int ks = 0; ks < 16; ks++) {
        int ko = ks*16 + kg*8;
        int off = (ko*2) ^ ((m & 15) << 4);
        short8 bh = *(const short8*)((const char*)sbh + m*512 + off);
        short8 bl = *(const short8*)((const char*)sbl + m*512 + off);
        short8 ah = *(const short8*)(W3hi + (size_t)(ch0+m)*256 + ko);
        short8 al = *(const short8*)(W3lo + (size_t)(ch0+m)*256 + ko);
        acc = mfma32(ah, bh, acc);
        acc = mfma32(ah, bl, acc);
        acc = mfma32(al, bh, acc);
    }
    #pragma unroll
    for (int q = 0; q < 4; q++) {
        ushort hs[4], ls[4];
        #pragma unroll
        for (int i = 0; i < 4; i++) {
            int r = q*4 + i;
            int chr = ch0 + i + 8*q + 4*kg;
            float v = fmaxf(fmaf(sS[chr], acc[r] + sB[chr], sT[chr]), 0.f);
            bsplit(v, hs[i], ls[i]);
        }
        int chb = ch0 + 8*q + 4*kg;
        int off = (chb*2) ^ ((m & 15) << 4);
        uint2 vh, vl;
        vh.x = (uint)hs[0] | ((uint)hs[1] << 16); vh.y = (uint)hs[2] | ((uint)hs[3] << 16);
        vl.x = (uint)ls[0] | ((uint)ls[1] << 16); vl.y = (uint)ls[2] | ((uint)ls[3] << 16);
        *(uint2*)((char*)a3h + m*256 + off) = vh;
        *(uint2*)((char*)a3l + m*256 + off) = vl;
    }
    __syncthreads();
    if (wv == 0) {
        f32x16 acc2 = {};
        for (int ks = 0; ks < 8; ks++) {
            int ko = ks*16 + kg*8;
            int off = (ko*2) ^ ((m & 15) << 4);
            short8 bh = *(const short8*)((const char*)a3h + m*256 + off);
            short8 bl = *(const short8*)((const char*)a3l + m*256 + off);
            short8 ah = *(const short8*)(W4hi + (size_t)m*128 + ko);
            short8 al = *(const short8*)(W4lo + (size_t)m*128 + ko);
            acc2 = mfma32(ah, bh, acc2);
            acc2 = mfma32(ah, bl, acc2);
            acc2 = mfma32(al, bh, acc2);
        }
        #pragma unroll
        for (int r = 0; r < 16; r++) {
            int mrow = (r&3) + 8*(r>>2) + 4*kg;
            if (mrow < 6) out[(size_t)(gn0+m)*6 + mrow] = acc2[r] + hb4[mrow];
        }
    }
}

extern "C" void kernel_launch(void* const* d_in, const int* in_sizes, int n_in,
                              void* d_out, int out_size, void* d_ws, size_t ws_size,
                              hipStream_t stream) {
    const float* pts  = (const float*)d_in[0];
    const float* w1   = (const float*)d_in[1];
    const float* b1   = (const float*)d_in[2];
    const float* g1   = (const float*)d_in[3];
    const float* be1  = (const float*)d_in[4];
    const float* w3   = (const float*)d_in[5];
    const float* b3   = (const float*)d_in[6];
    const float* g3   = (const float*)d_in[7];
    const float* be3  = (const float*)d_in[8];
    const float* hw1  = (const float*)d_in[9];
    const float* hb1  = (const float*)d_in[10];
    const float* hg1  = (const float*)d_in[11];
    const float* hbe1 = (const float*)d_in[12];
    const float* hw2  = (const float*)d_in[13];
    const float* hb2  = (const float*)d_in[14];
    const float* hg2  = (const float*)d_in[15];
    const float* hbe2 = (const float*)d_in[16];
    const float* hw3  = (const float*)d_in[17];
    const float* hb3  = (const float*)d_in[18];
    const float* hg3  = (const float*)d_in[19];
    const float* hbe3 = (const float*)d_in[20];
    const float* hw4  = (const float*)d_in[21];
    const float* hb4  = (const float*)d_in[22];
    (void)in_sizes; (void)n_in; (void)out_size; (void)ws_size;

    float* W = (float*)d_ws;
    size_t off = 0;
    auto alloc = [&](size_t n) { float* p = W + off; off += n; return p; };
    auto allocU = [&](size_t nshorts) { return (ushort*)alloc((nshorts + 1) / 2); };

    ushort* lfh  = allocU(65536UL*64);
    ushort* lfl  = allocU(65536UL*64);
    ushort* a2h  = allocU(65536UL*256);
    ushort* a2l  = allocU(65536UL*256);
    ushort* w3h  = allocU(512*64);  ushort* w3l  = allocU(512*64);
    ushort* w1eh = allocU(512*64);  ushort* w1el = allocU(512*64);
    ushort* w2h  = allocU(256*512); ushort* w2l  = allocU(256*512);
    ushort* wh3h = allocU(128*256); ushort* wh3l = allocU(128*256);
    ushort* w4h  = allocU(32*128);  ushort* w4l  = allocU(32*128);
    float* y38    = alloc(524288);
    float* mbuf   = alloc(65536);
    float* gmaxb  = alloc(8192);
    float* G1     = alloc(8192);
    float* A1     = alloc(512);
    float* s1 = alloc(64);  float* t1 = alloc(64);
    float* s3 = alloc(512); float* t3 = alloc(512);
    float* sh1 = alloc(512); float* th1 = alloc(512);
    float* sh2 = alloc(256); float* th2 = alloc(256);
    float* sh3 = alloc(128); float* th3 = alloc(128);
    float* part1  = alloc(32768);
    float* part3  = alloc(512*1536);
    float* parth1 = alloc(512*1024);
    float* parth2 = alloc(2048*512);
    float* parth3 = alloc(512*256);
    float* pre2   = alloc(16777216);

    k_wsplit<<<128, 256, 0, stream>>>(w3, 64, 0, 512, 64, w3h, w3l, 512);
    k_wsplit<<<128, 256, 0, stream>>>(hw1, 1088, 512, 512, 64, w1eh, w1el, 512);
    k_wsplit<<<512, 256, 0, stream>>>(hw2, 512, 0, 256, 512, w2h, w2l, 256);
    k_wsplit<<<128, 256, 0, stream>>>(hw3, 256, 0, 128, 256, wh3h, wh3l, 128);
    k_wsplit<<<16, 256, 0, stream>>>(hw4, 128, 0, 6, 128, w4h, w4l, 32);

    k_stats1<<<256, 256, 0, stream>>>(pts, w1, b1, part1);
    k_fin<<<64, 256, 0, stream>>>(part1, 256, 128, 64, g1, be1, s1, t1);
    k_lfeat2<<<256, 256, 0, stream>>>(pts, w1, b1, s1, t1, lfh, lfl);
    k_gemm64<0><<<512, 256, 0, stream>>>(lfh, lfl, w3h, w3l, b3, nullptr, nullptr, nullptr, part3, y38);
    k_fin<<<512, 256, 0, stream>>>(part3, 512, 1536, 512, g3, be3, s3, t3);
    k_fin3b<<<16, 512, 0, stream>>>(part3, s3, t3, gmaxb);
    k_a1g1<<<17, 256, 0, stream>>>(hw1, gmaxb, A1, G1);
    k_knn<<<2048, 256, 0, stream>>>(pts, y38, s3, t3, mbuf);
    k_gemm64<1><<<512, 256, 0, stream>>>(lfh, lfl, w1eh, w1el, hb1, A1, G1, mbuf, parth1, nullptr);
    k_fin<<<512, 256, 0, stream>>>(parth1, 512, 1024, 512, hg1, hbe1, sh1, th1);
    k_h2m<<<2048, 256, 0, stream>>>(lfh, lfl, w1eh, w1el, w2h, w2l, hb1, A1, G1, mbuf,
                                    sh1, th1, hb2, pre2, parth2);
    k_fin<<<256, 256, 0, stream>>>(parth2, 2048, 512, 256, hg2, hbe2, sh2, th2);
    k_a2t<<<16384, 256, 0, stream>>>(pre2, sh2, th2, a2h, a2l);
    k_h3s<<<512, 256, 0, stream>>>(a2h, a2l, wh3h, wh3l, hb3, parth3);
    k_fin<<<128, 256, 0, stream>>>(parth3, 512, 256, 128, hg3, hbe3, sh3, th3);
    k_h4m<<<2048, 256, 0, stream>>>(a2h, a2l, wh3h, wh3l, hb3, sh3, th3, w4h, w4l, hb4, (float*)d_out);
}